// Round 3
// baseline (418.612 us; speedup 1.0000x reference)
//
#include <hip/hip_runtime.h>
#include <cstdint>
#include <cstddef>

#define Tt 2048
#define Cc 1024
#define Ss 256

using short8 = __attribute__((ext_vector_type(8))) short;
using f32x4  = __attribute__((ext_vector_type(4))) float;
typedef const __attribute__((address_space(1))) void* as1_cvp;
typedef __attribute__((address_space(3))) void* as3_vp;

__device__ __forceinline__ unsigned short f2bf(float f) {
  unsigned int u = __float_as_uint(f);
  u += 0x7fffu + ((u >> 16) & 1u);
  return (unsigned short)(u >> 16);
}
__device__ __forceinline__ float bf2f(unsigned short h) {
  return __uint_as_float(((unsigned)h) << 16);
}
// 3-way split: v = h + m + l to ~2^-24 relative
__device__ __forceinline__ void split3(float v, unsigned short& h, unsigned short& m, unsigned short& l) {
  h = f2bf(v);
  float r = v - bf2f(h);
  m = f2bf(r);
  l = f2bf(r - bf2f(m));
}

// LDS short-offset for 64-row x 32-short tile, chunk-XOR swizzled (2-way bank
// aliasing on ds_read_b128 = free, m136)
__device__ __forceinline__ int sw32(int row, int q) {
  return row * 32 + ((q ^ ((row >> 1) & 3)) << 3);
}

// slots planes = split3(mean over 8 consecutive t rows)
__global__ __launch_bounds__(256) void poolsplit_k(const float* __restrict__ x, unsigned short* __restrict__ sp) {
  const long PS2 = 2048l * 1024;
  const int sli = blockIdx.x;           // b*256+s
  const int c = threadIdx.x << 2;
  const float* src = x + (size_t)sli * 8 * Cc + c;
  float a[4] = {0.f, 0.f, 0.f, 0.f};
#pragma unroll
  for (int j = 0; j < 8; j++) {
    float4 v = *(const float4*)(src + (size_t)j * Cc);
    a[0] += v.x; a[1] += v.y; a[2] += v.z; a[3] += v.w;
  }
  unsigned short h[4], m[4], l[4];
#pragma unroll
  for (int e = 0; e < 4; e++) split3(a[e] * 0.125f, h[e], m[e], l[e]);
  size_t o = (size_t)sli * Cc + c;
  *(uint2*)&sp[o]           = uint2{(unsigned)h[0] | ((unsigned)h[1] << 16), (unsigned)h[2] | ((unsigned)h[3] << 16)};
  *(uint2*)&sp[o + PS2]     = uint2{(unsigned)m[0] | ((unsigned)m[1] << 16), (unsigned)m[2] | ((unsigned)m[3] << 16)};
  *(uint2*)&sp[o + 2 * PS2] = uint2{(unsigned)l[0] | ((unsigned)l[1] << 16), (unsigned)l[2] | ((unsigned)l[3] << 16)};
}

// Transpose + split: dst[p][e][d] = split3(src[d][e]), npl planes written.
__global__ __launch_bounds__(256) void split_t_k(const float* __restrict__ src, unsigned short* __restrict__ dst,
                                                 long pstride, int npl) {
  __shared__ unsigned short th[64][68], tm[64][68], tl[64][68];
  const int r0 = blockIdx.y << 6, c0 = blockIdx.x << 6;
  const int tid = threadIdx.x;
#pragma unroll
  for (int p = 0; p < 4; p++) {
    int r = (p << 4) + (tid >> 4);
    int c = (tid & 15) << 2;
    float4 v = *(const float4*)&src[(size_t)(r0 + r) * Cc + c0 + c];
    unsigned short h, m, l;
    split3(v.x, h, m, l); th[c + 0][r] = h; tm[c + 0][r] = m; tl[c + 0][r] = l;
    split3(v.y, h, m, l); th[c + 1][r] = h; tm[c + 1][r] = m; tl[c + 1][r] = l;
    split3(v.z, h, m, l); th[c + 2][r] = h; tm[c + 2][r] = m; tl[c + 2][r] = l;
    split3(v.w, h, m, l); th[c + 3][r] = h; tm[c + 3][r] = m; tl[c + 3][r] = l;
  }
  __syncthreads();
#pragma unroll
  for (int p = 0; p < 4; p++) {
    int r = (p << 4) + (tid >> 4);      // dst row = src col
    int c = (tid & 15) << 2;
    size_t o = (size_t)(c0 + r) * Cc + r0 + c;
    *(uint2*)&dst[o] = uint2{(unsigned)th[r][c] | ((unsigned)th[r][c+1] << 16),
                             (unsigned)th[r][c+2] | ((unsigned)th[r][c+3] << 16)};
    *(uint2*)&dst[o + pstride] = uint2{(unsigned)tm[r][c] | ((unsigned)tm[r][c+1] << 16),
                                       (unsigned)tm[r][c+2] | ((unsigned)tm[r][c+3] << 16)};
    if (npl == 3)
      *(uint2*)&dst[o + 2 * pstride] = uint2{(unsigned)tl[r][c] | ((unsigned)tl[r][c+1] << 16),
                                             (unsigned)tl[r][c+2] | ((unsigned)tl[r][c+3] << 16)};
  }
}

// Plain split, npl planes
__global__ __launch_bounds__(256) void split_k(const float* __restrict__ src, unsigned short* __restrict__ dst,
                                               long pstride, int npl) {
  int id = blockIdx.x * 256 + threadIdx.x;
  int c = id << 2;
  float4 v = *(const float4*)&src[c];
  unsigned short h[4], m[4], l[4];
  split3(v.x, h[0], m[0], l[0]); split3(v.y, h[1], m[1], l[1]);
  split3(v.z, h[2], m[2], l[2]); split3(v.w, h[3], m[3], l[3]);
  *(uint2*)&dst[c] = uint2{(unsigned)h[0] | ((unsigned)h[1] << 16), (unsigned)h[2] | ((unsigned)h[3] << 16)};
  *(uint2*)&dst[c + pstride] = uint2{(unsigned)m[0] | ((unsigned)m[1] << 16), (unsigned)m[2] | ((unsigned)m[3] << 16)};
  if (npl == 3)
    *(uint2*)&dst[c + 2 * pstride] = uint2{(unsigned)l[0] | ((unsigned)l[1] << 16), (unsigned)l[2] | ((unsigned)l[3] << 16)};
}

// Multi-plane split GEMM body: C = scale * A @ B^T with A,B as NPL bf16 planes.
// NT=6: products hh,hm,mh,hl,lh,mm (error ~2^-24). NT=3: hh,hm,mh (~2^-16).
// 64x64 tile, BK=32, 4 waves of 32x32. global_load_lds width-16 staging,
// double-buffered (T3 minimum 2-phase).
template<int NT, int SPLIT_OUT>
__device__ __forceinline__ void gemm3_body(const unsigned short* __restrict__ Ap, long apl,
                                           const unsigned short* __restrict__ Bp, long bpl,
                                           float* __restrict__ C,
                                           unsigned short* __restrict__ Cs, long cpl,
                                           float scale) {
  constexpr int NPL = (NT == 6) ? 3 : 2;
  constexpr int BUFS = 2 * NPL * 2048;              // shorts per buffer
  __shared__ unsigned short LDS[2 * BUFS];          // double-buffered A+B planes
  const int tid = threadIdx.x, lane = tid & 63, wid = tid >> 6;
  const int m0 = blockIdx.y << 6, n0 = blockIdx.x << 6;

  const unsigned short* sp[2 * NPL];
  int dof[2 * NPL];                                  // byte offset within a buffer
#pragma unroll
  for (int i = 0; i < 2 * NPL; i++) {
    int s = wid * 2 * NPL + i;           // [0, 8*NPL)
    int tile = s >> 2;                   // [0, 2*NPL)
    int ci = ((s & 3) << 6) | lane;      // chunk in tile [0,256)
    int row = ci >> 2;
    int q = (ci & 3) ^ ((row >> 1) & 3); // source chunk for swizzled slot
    int isB = tile >= NPL;
    int pl = isB ? tile - NPL : tile;
    const unsigned short* base = isB ? (Bp + (size_t)pl * bpl) : (Ap + (size_t)pl * apl);
    int r0 = isB ? n0 : m0;
    sp[i] = base + (size_t)(r0 + row) * Cc + (q << 3);
    dof[i] = (tile * 2048 + ((s & 3) << 9)) * 2;
  }

  const int wm = (wid >> 1) << 5, wn = (wid & 1) << 5;
  const int lm = lane & 15, lq = lane >> 4;
  constexpr int PA[6] = {0, 0, 1, 0, 2, 1};
  constexpr int PB[6] = {0, 1, 0, 2, 0, 1};
  const f32x4 zero = {0.f, 0.f, 0.f, 0.f};
  f32x4 acc[2][2] = {{zero, zero}, {zero, zero}};

  // prologue: stage K-tile 0 into buf 0
#pragma unroll
  for (int i = 0; i < 2 * NPL; i++) {
    __builtin_amdgcn_global_load_lds((as1_cvp)sp[i], (as3_vp)((char*)LDS + dof[i]), 16, 0, 0);
    sp[i] += 32;
  }
  __syncthreads();

  int cur = 0;
  for (int k0 = 0; k0 < Cc; k0 += 32) {
    if (k0 + 32 < Cc) {                  // issue next tile's loads (prefetch)
      const int nb = (cur ^ 1) * (BUFS * 2);
#pragma unroll
      for (int i = 0; i < 2 * NPL; i++) {
        __builtin_amdgcn_global_load_lds((as1_cvp)sp[i], (as3_vp)((char*)LDS + nb + dof[i]), 16, 0, 0);
        sp[i] += 32;
      }
    }
    const int cb = cur * BUFS;           // shorts
    short8 af[2][NPL], bf[2][NPL];
#pragma unroll
    for (int i = 0; i < 2; i++)
#pragma unroll
      for (int p = 0; p < NPL; p++) {
        af[i][p] = *(const short8*)&LDS[cb + p * 2048 + sw32(wm + (i << 4) + lm, lq)];
        bf[i][p] = *(const short8*)&LDS[cb + (NPL + p) * 2048 + sw32(wn + (i << 4) + lm, lq)];
      }
#pragma unroll
    for (int i = 0; i < 2; i++)
#pragma unroll
      for (int j = 0; j < 2; j++)
#pragma unroll
        for (int t = 0; t < NT; t++)
          acc[i][j] = __builtin_amdgcn_mfma_f32_16x16x32_bf16(af[i][PA[t]], bf[j][PB[t]], acc[i][j], 0, 0, 0);
    __syncthreads();                     // drains vmcnt(0): next buf staged
    cur ^= 1;
  }
  // C/D: col = lane&15, row = (lane>>4)*4 + reg  [m89-verified]
#pragma unroll
  for (int i = 0; i < 2; i++)
#pragma unroll
    for (int j = 0; j < 2; j++)
#pragma unroll
      for (int r = 0; r < 4; r++) {
        int gr = m0 + wm + (i << 4) + (lq << 2) + r;
        int gc = n0 + wn + (j << 4) + lm;
        size_t o = (size_t)gr * Cc + gc;
        float v = acc[i][j][r] * scale;
        if (SPLIT_OUT) {
          unsigned short h = f2bf(v);
          float rr = v - bf2f(h);
          unsigned short mm2 = f2bf(rr);
          Cs[o] = h;
          Cs[o + cpl] = mm2;
          if (NPL == 3) Cs[o + 2 * (size_t)cpl] = f2bf(rr - bf2f(mm2));
        } else {
          C[o] = v;
        }
      }
}

// Concrete wrappers (no template __global__ — see round-5 link failure)
__global__ __launch_bounds__(256) void gemm3_61_k(const unsigned short* __restrict__ Ap, long apl,
                                                  const unsigned short* __restrict__ Bp, long bpl,
                                                  unsigned short* __restrict__ Cs, long cpl, float scale) {
  gemm3_body<6, 1>(Ap, apl, Bp, bpl, nullptr, Cs, cpl, scale);
}
__global__ __launch_bounds__(256) void gemm3_31_k(const unsigned short* __restrict__ Ap, long apl,
                                                  const unsigned short* __restrict__ Bp, long bpl,
                                                  unsigned short* __restrict__ Cs, long cpl, float scale) {
  gemm3_body<3, 1>(Ap, apl, Bp, bpl, nullptr, Cs, cpl, scale);
}
__global__ __launch_bounds__(256) void gemm3_30_k(const unsigned short* __restrict__ Ap, long apl,
                                                  const unsigned short* __restrict__ Bp, long bpl,
                                                  float* __restrict__ C, float scale) {
  gemm3_body<3, 0>(Ap, apl, Bp, bpl, C, nullptr, 0, scale);
}

// Fused scores + per-half top-8. 64 t-rows x 128 slots per block, 512 thr
// (8 waves, 2 row-groups x 4 col-groups of 32x32 output each).
// HALF-SLOT SPLIT for occupancy: LDS 76800 B -> 2 blocks/CU (16 waves/CU), so
// the per-step __syncthreads vmcnt-drain of one block is overlapped by the
// other block's compute (m114 mechanism; was 1 block/CU = fully exposed).
// BK=32 double-buffered: kq 3 planes via global_load_lds (2x24 KB), x staged
// to regs + split3 written late into padded LDS planes (2x13.5 KB).
// Emits per-half top-8 (scaled score + global slot idx) -> topmerge_k.
// Grid: 512 blocks, b = bid&7 -> batch-to-XCD affinity for kq L2 locality.
__global__ __launch_bounds__(512, 4) void scores_topk_k(const float* __restrict__ x,
                                                        const unsigned short* __restrict__ kqp,
                                                        float* __restrict__ hv, int* __restrict__ hi) {
  __shared__ __align__(16) char smem[76800];
  unsigned short* lds16 = (unsigned short*)smem;
  float* sc = (float*)smem;                         // tail: 64x132 fp32 (aliases kq bufs)

  const int tid = threadIdx.x, lane = tid & 63, wid = tid >> 6;
  const int bid = blockIdx.x;
  const int b = bid & 7, half = (bid >> 3) & 1, tt = bid >> 4;
  const int s0 = half << 7;                         // slot range base

  // kq staging: 24 slots (3 planes x 8 sub-tiles of 1 KB), 3 per wave
  const char* ksrc[3];
  int kdst[3];                                      // byte offset within a kq buffer
#pragma unroll
  for (int i = 0; i < 3; i++) {
    int s = wid * 3 + i;                 // [0,24)
    int p = s >> 3, sub = s & 7;
    int ci = (sub << 6) | lane;          // [0,512)
    int row = ci >> 2;                   // [0,128)
    int q = (ci & 3) ^ ((row >> 1) & 3);
    ksrc[i] = (const char*)(kqp + (size_t)p * (2048l * 1024) + ((size_t)b * Ss + s0 + row) * Cc + (q << 3));
    kdst[i] = p * 8192 + sub * 1024;
  }
  const int spr = tid >> 3, spk = (tid & 7) << 2;   // x-tile: row, col(4 floats)
  const float* xsrc = x + ((size_t)b * Tt + (size_t)tt * 64 + spr) * Cc + spk;

  const int wm = (wid & 1) << 5;         // row group (2 x 32 rows)
  const int wn = (wid >> 1) << 5;        // col group (4 x 32 cols)
  const int lm = lane & 15, lq = lane >> 4;
  const int XPs = 24576;                 // x-plane base (shorts); buf stride 6912, plane 2304
  const int KQB = 24576;                 // kq buffer stride (bytes); 12288 shorts

  constexpr int PA[6] = {0, 0, 1, 0, 2, 1};
  constexpr int PB[6] = {0, 1, 0, 2, 0, 1};
  const f32x4 zero = {0.f, 0.f, 0.f, 0.f};
  f32x4 acc[2][2] = {{zero, zero}, {zero, zero}};

  // ---- prologue: stage K-tile 0
  {
    float4 xv = *(const float4*)xsrc; xsrc += 32;
#pragma unroll
    for (int i = 0; i < 3; i++) {
      __builtin_amdgcn_global_load_lds((as1_cvp)ksrc[i], (as3_vp)(smem + kdst[i]), 16, 0, 0);
      ksrc[i] += 64;
    }
    unsigned short h[4], m[4], l[4];
    split3(xv.x, h[0], m[0], l[0]); split3(xv.y, h[1], m[1], l[1]);
    split3(xv.z, h[2], m[2], l[2]); split3(xv.w, h[3], m[3], l[3]);
    int o = XPs + spr * 36 + spk;
    *(uint2*)&lds16[o]        = uint2{(unsigned)h[0] | ((unsigned)h[1] << 16), (unsigned)h[2] | ((unsigned)h[3] << 16)};
    *(uint2*)&lds16[o + 2304] = uint2{(unsigned)m[0] | ((unsigned)m[1] << 16), (unsigned)m[2] | ((unsigned)m[3] << 16)};
    *(uint2*)&lds16[o + 4608] = uint2{(unsigned)l[0] | ((unsigned)l[1] << 16), (unsigned)l[2] | ((unsigned)l[3] << 16)};
  }
  __syncthreads();

  int cur = 0;
  for (int ks = 0; ks < 32; ks++) {
    const int nb = cur ^ 1;
    float4 xv2;
    if (ks < 31) {                       // issue next tile's loads (prefetch)
      xv2 = *(const float4*)xsrc; xsrc += 32;
#pragma unroll
      for (int i = 0; i < 3; i++) {
        __builtin_amdgcn_global_load_lds((as1_cvp)ksrc[i], (as3_vp)(smem + nb * KQB + kdst[i]), 16, 0, 0);
        ksrc[i] += 64;
      }
    }
    // ---- compute current tile
    const int xb = XPs + cur * 6912;     // shorts
    const int kb = cur * 12288;          // shorts
    short8 afr[2][3], bfr[2][3];
#pragma unroll
    for (int i = 0; i < 2; i++)
#pragma unroll
      for (int p = 0; p < 3; p++)
        afr[i][p] = *(const short8*)&lds16[xb + p * 2304 + (wm + (i << 4) + lm) * 36 + (lq << 3)];
#pragma unroll
    for (int j = 0; j < 2; j++) {
      int br = wn + (j << 4) + lm;       // [0,128)
      int bo = (br << 5) + ((lq ^ ((br >> 1) & 3)) << 3);
#pragma unroll
      for (int p = 0; p < 3; p++)
        bfr[j][p] = *(const short8*)&lds16[kb + p * 4096 + bo];
    }
#pragma unroll
    for (int i = 0; i < 2; i++)
#pragma unroll
      for (int j = 0; j < 2; j++)
#pragma unroll
        for (int t = 0; t < 6; t++)
          acc[i][j] = __builtin_amdgcn_mfma_f32_16x16x32_bf16(afr[i][PA[t]], bfr[j][PB[t]], acc[i][j], 0, 0, 0);
    // ---- split next x tile into planes buf nb (write-late; regs only)
    if (ks < 31) {
      unsigned short h[4], m[4], l[4];
      split3(xv2.x, h[0], m[0], l[0]); split3(xv2.y, h[1], m[1], l[1]);
      split3(xv2.z, h[2], m[2], l[2]); split3(xv2.w, h[3], m[3], l[3]);
      int o = XPs + nb * 6912 + spr * 36 + spk;
      *(uint2*)&lds16[o]        = uint2{(unsigned)h[0] | ((unsigned)h[1] << 16), (unsigned)h[2] | ((unsigned)h[3] << 16)};
      *(uint2*)&lds16[o + 2304] = uint2{(unsigned)m[0] | ((unsigned)m[1] << 16), (unsigned)m[2] | ((unsigned)m[3] << 16)};
      *(uint2*)&lds16[o + 4608] = uint2{(unsigned)l[0] | ((unsigned)l[1] << 16), (unsigned)l[2] | ((unsigned)l[3] << 16)};
    }
    __syncthreads();                     // next kq buf staged; plane writes visible
    cur ^= 1;
  }

  // scores -> LDS (scaled 1/32), then per-wave top-8 over this half
#pragma unroll
  for (int i = 0; i < 2; i++)
#pragma unroll
    for (int j = 0; j < 2; j++)
#pragma unroll
      for (int r = 0; r < 4; r++)
        sc[(wm + (i << 4) + (lq << 2) + r) * 132 + wn + (j << 4) + lm] = acc[i][j][r] * 0.03125f;
  __syncthreads();

  for (int r2 = 0; r2 < 8; r2++) {
    int row = (wid << 3) + r2;
    float2 v2 = *(const float2*)(sc + row * 132 + (lane << 1));
    float cand[2] = {v2.x, v2.y};
    float topv[8]; int tops[8];
#pragma unroll
    for (int k = 0; k < 8; k++) {
      float bv = -1e30f; int bs = 1 << 20;
#pragma unroll
      for (int e = 0; e < 2; e++) {
        int s = (lane << 1) + e;
        if (cand[e] > bv || (cand[e] == bv && s < bs)) { bv = cand[e]; bs = s; }
      }
#pragma unroll
      for (int m = 32; m >= 1; m >>= 1) {
        float ov = __shfl_xor(bv, m, 64);
        int   os = __shfl_xor(bs, m, 64);
        if (ov > bv || (ov == bv && os < bs)) { bv = ov; bs = os; }
      }
      topv[k] = bv; tops[k] = bs;
      if ((bs >> 1) == lane) cand[bs & 1] = -1e30f;
    }
    if (lane < 8) {
      float myv = topv[0]; int myi = tops[0];
#pragma unroll
      for (int k = 1; k < 8; k++) if (lane == k) { myv = topv[k]; myi = tops[k]; }
      size_t trow = (size_t)b * Tt + (size_t)tt * 64 + row;
      hv[trow * 16 + (half << 3) + lane] = myv;
      hi[trow * 16 + (half << 3) + lane] = s0 + myi;
    }
  }
}

// Merge two per-half top-8 lists -> global top-8 + softmax weights.
// One thread per t-row. Comparison-based clear (no runtime-indexed array
// store -> stays in registers, rule #20).
__global__ __launch_bounds__(256) void topmerge_k(const float* __restrict__ hv, const int* __restrict__ hi,
                                                  float* __restrict__ topw, int* __restrict__ topi) {
  const int row = blockIdx.x * 256 + threadIdx.x;   // [0,16384)
  float v[16]; int ix[16];
#pragma unroll
  for (int g = 0; g < 4; g++) {
    float4 a = *(const float4*)(hv + (size_t)row * 16 + (g << 2));
    int4  c = *(const int4*)(hi + (size_t)row * 16 + (g << 2));
    v[(g << 2) + 0] = a.x; v[(g << 2) + 1] = a.y; v[(g << 2) + 2] = a.z; v[(g << 2) + 3] = a.w;
    ix[(g << 2) + 0] = c.x; ix[(g << 2) + 1] = c.y; ix[(g << 2) + 2] = c.z; ix[(g << 2) + 3] = c.w;
  }
  float ov[8]; int oi[8];
#pragma unroll
  for (int k = 0; k < 8; k++) {
    float bv = -1e30f; int bi = 1 << 30;
#pragma unroll
    for (int e = 0; e < 16; e++)
      if (v[e] > bv || (v[e] == bv && ix[e] < bi)) { bv = v[e]; bi = ix[e]; }
    ov[k] = bv; oi[k] = bi;
#pragma unroll
    for (int e = 0; e < 16; e++)
      if (v[e] == bv && ix[e] == bi) v[e] = -1e30f;
  }
  const float mx = ov[0];
  float w[8]; float sum = 0.f;
#pragma unroll
  for (int k = 0; k < 8; k++) { w[k] = expf(ov[k] - mx); sum += w[k]; }
  const float inv = 1.f / sum;
#pragma unroll
  for (int k = 0; k < 8; k++) {
    topw[(size_t)row * 8 + k] = w[k] * inv;
    topi[(size_t)row * 8 + k] = oi[k];
  }
}

// out[row,:] = 0.5 * sum_k w_k * u[b*256+idx_k, :]   (fp32)
__global__ __launch_bounds__(256) void gatherout_k(const float* __restrict__ u, const float* __restrict__ topw,
                                                   const int* __restrict__ topi, float* __restrict__ out) {
  __shared__ float w[8];
  __shared__ int  id8[8];
  const int row = blockIdx.x;
  const int b = row >> 11;
  if (threadIdx.x < 8) {
    w[threadIdx.x]   = topw[(size_t)row * 8 + threadIdx.x];
    id8[threadIdx.x] = topi[(size_t)row * 8 + threadIdx.x];
  }
  __syncthreads();
  int c = threadIdx.x << 2;
  float ax = 0.f, ay = 0.f, az = 0.f, aw = 0.f;
#pragma unroll
  for (int j = 0; j < 8; j++) {
    const float4 vv = *(const float4*)&u[((size_t)(b << 8) + id8[j]) * Cc + c];
    float wj = w[j];
    ax = fmaf(wj, vv.x, ax); ay = fmaf(wj, vv.y, ay);
    az = fmaf(wj, vv.z, az); aw = fmaf(wj, vv.w, aw);
  }
  *(float4*)&out[(size_t)row * Cc + c] = make_float4(ax * 0.5f, ay * 0.5f, az * 0.5f, aw * 0.5f);
}

extern "C" void kernel_launch(void* const* d_in, const int* in_sizes, int n_in,
                              void* d_out, int out_size, void* d_ws, size_t ws_size,
                              hipStream_t stream) {
  (void)in_sizes; (void)n_in; (void)out_size; (void)ws_size;
  const float* x  = (const float*)d_in[0];
  const float* Wq = (const float*)d_in[1];
  const float* Wk = (const float*)d_in[2];
  const float* Wv = (const float*)d_in[3];
  const float* Wp = (const float*)d_in[4];
  float* out = (float*)d_out;

  char* ws = (char*)d_ws;
  const size_t MB = 1ull << 20;
  const long PS1 = 1024l * 1024;   // plane stride, 1024x1024 (shorts)
  const long PS2 = 2048l * 1024;   // plane stride, 2048x1024 (shorts)
  unsigned short* slotp = (unsigned short*)(ws + 0 * MB);   // 12 MB: 3 planes [2048x1024]
  unsigned short* Wqt   = (unsigned short*)(ws + 12 * MB);  // 6 MB: 3 planes [c][d]
  unsigned short* Wkt   = (unsigned short*)(ws + 18 * MB);  // 6 MB: 3 planes [e][d]
  unsigned short* Wvt   = (unsigned short*)(ws + 24 * MB);  // 4 MB: 2 planes [e][d]
  unsigned short* Wpp   = (unsigned short*)(ws + 28 * MB);  // 4 MB: 2 planes [o][d]
  unsigned short* MtT   = (unsigned short*)(ws + 32 * MB);  // 6 MB: 3 planes [c][e] = (Wk^T Wq)^T
  unsigned short* kqp   = (unsigned short*)(ws + 38 * MB);  // 12 MB: 3 planes [2048x1024]
  unsigned short* W2p   = (unsigned short*)(ws + 50 * MB);  // 4 MB: 2 planes [o][e] = Wp@Wv
  float*          u     = (float*)(ws + 54 * MB);           // 8 MB fp32 [2048x1024]
  float*          topw  = (float*)(ws + 62 * MB);           // 0.5 MB
  int*            topi  = (int*)(ws + 62 * MB + 512 * 1024);// 0.5 MB
  float*          hv    = (float*)(ws + 63 * MB);           // 1 MB: per-half top-8 scores [16384x16]
  int*            hi    = (int*)(ws + 64 * MB);             // 1 MB: per-half top-8 indices -> 65 MB total

  // 1. pool + split3 slots (x read once here)
  poolsplit_k<<<2048, 256, 0, stream>>>(x, slotp);
  // 2. transpose+split weights
  split_t_k<<<dim3(16, 16), 256, 0, stream>>>(Wq, Wqt, PS1, 3);
  split_t_k<<<dim3(16, 16), 256, 0, stream>>>(Wk, Wkt, PS1, 3);
  split_t_k<<<dim3(16, 16), 256, 0, stream>>>(Wv, Wvt, PS1, 2);
  split_k<<<1024, 256, 0, stream>>>(Wp, Wpp, PS1, 2);
  // 3. MtT[c][e] = sum_d Wq[d][c]*Wk[d][e]   (6-product, split3 out)
  gemm3_61_k<<<dim3(16, 16), 256, 0, stream>>>(Wqt, PS1, Wkt, PS1, MtT, PS1, 1.0f);
  // 4. kq[s][c] = sum_e slots[s][e]*MtT[c][e] (6-product, split3 out)
  gemm3_61_k<<<dim3(16, 32), 256, 0, stream>>>(slotp, PS2, MtT, PS1, kqp, PS2, 1.0f);
  // 5. W2[o][e] = sum_d Wp[o][d]*Wvt[e][d]    (3-product, split2 out)
  gemm3_31_k<<<dim3(16, 16), 256, 0, stream>>>(Wpp, PS1, Wvt, PS1, W2p, PS1, 1.0f);
  // 6. u[s][o] = sum_e slots[s][e]*W2[o][e]   (3-product, fp32 out)
  gemm3_30_k<<<dim3(16, 32), 256, 0, stream>>>(slotp, PS2, W2p, PS1, u, 1.0f);
  // 7. fused scores (6-product, half-slot split, 2 blocks/CU) + per-half top-8
  scores_topk_k<<<512, 512, 0, stream>>>(x, kqp, hv, hi);
  // 7b. merge halves + softmax
  topmerge_k<<<64, 256, 0, stream>>>(hv, hi, topw, topi);
  // 8. gather + 0.5 scale
  gatherout_k<<<16384, 256, 0, stream>>>(u, topw, topi, out);
}

// Round 4
// 404.618 us; speedup vs baseline: 1.0346x; 1.0346x over previous
//
#include <hip/hip_runtime.h>
#include <cstdint>
#include <cstddef>

#define Tt 2048
#define Cc 1024
#define Ss 256

using short8 = __attribute__((ext_vector_type(8))) short;
using f32x4  = __attribute__((ext_vector_type(4))) float;
typedef const __attribute__((address_space(1))) void* as1_cvp;
typedef __attribute__((address_space(3))) void* as3_vp;

__device__ __forceinline__ unsigned short f2bf(float f) {
  unsigned int u = __float_as_uint(f);
  u += 0x7fffu + ((u >> 16) & 1u);
  return (unsigned short)(u >> 16);
}
__device__ __forceinline__ float bf2f(unsigned short h) {
  return __uint_as_float(((unsigned)h) << 16);
}
// 3-way split: v = h + m + l to ~2^-24 relative
__device__ __forceinline__ void split3(float v, unsigned short& h, unsigned short& m, unsigned short& l) {
  h = f2bf(v);
  float r = v - bf2f(h);
  m = f2bf(r);
  l = f2bf(r - bf2f(m));
}

// LDS short-offset for 64-row x 32-short tile, chunk-XOR swizzled (2-way bank
// aliasing on ds_read_b128 = free, m136)
__device__ __forceinline__ int sw32(int row, int q) {
  return row * 32 + ((q ^ ((row >> 1) & 3)) << 3);
}

// slots planes = split3(mean over 8 consecutive t rows)
__global__ __launch_bounds__(256) void poolsplit_k(const float* __restrict__ x, unsigned short* __restrict__ sp) {
  const long PS2 = 2048l * 1024;
  const int sli = blockIdx.x;           // b*256+s
  const int c = threadIdx.x << 2;
  const float* src = x + (size_t)sli * 8 * Cc + c;
  float a[4] = {0.f, 0.f, 0.f, 0.f};
#pragma unroll
  for (int j = 0; j < 8; j++) {
    float4 v = *(const float4*)(src + (size_t)j * Cc);
    a[0] += v.x; a[1] += v.y; a[2] += v.z; a[3] += v.w;
  }
  unsigned short h[4], m[4], l[4];
#pragma unroll
  for (int e = 0; e < 4; e++) split3(a[e] * 0.125f, h[e], m[e], l[e]);
  size_t o = (size_t)sli * Cc + c;
  *(uint2*)&sp[o]           = uint2{(unsigned)h[0] | ((unsigned)h[1] << 16), (unsigned)h[2] | ((unsigned)h[3] << 16)};
  *(uint2*)&sp[o + PS2]     = uint2{(unsigned)m[0] | ((unsigned)m[1] << 16), (unsigned)m[2] | ((unsigned)m[3] << 16)};
  *(uint2*)&sp[o + 2 * PS2] = uint2{(unsigned)l[0] | ((unsigned)l[1] << 16), (unsigned)l[2] | ((unsigned)l[3] << 16)};
}

// Transpose + split: dst[p][e][d] = split3(src[d][e]), npl planes written.
__global__ __launch_bounds__(256) void split_t_k(const float* __restrict__ src, unsigned short* __restrict__ dst,
                                                 long pstride, int npl) {
  __shared__ unsigned short th[64][68], tm[64][68], tl[64][68];
  const int r0 = blockIdx.y << 6, c0 = blockIdx.x << 6;
  const int tid = threadIdx.x;
#pragma unroll
  for (int p = 0; p < 4; p++) {
    int r = (p << 4) + (tid >> 4);
    int c = (tid & 15) << 2;
    float4 v = *(const float4*)&src[(size_t)(r0 + r) * Cc + c0 + c];
    unsigned short h, m, l;
    split3(v.x, h, m, l); th[c + 0][r] = h; tm[c + 0][r] = m; tl[c + 0][r] = l;
    split3(v.y, h, m, l); th[c + 1][r] = h; tm[c + 1][r] = m; tl[c + 1][r] = l;
    split3(v.z, h, m, l); th[c + 2][r] = h; tm[c + 2][r] = m; tl[c + 2][r] = l;
    split3(v.w, h, m, l); th[c + 3][r] = h; tm[c + 3][r] = m; tl[c + 3][r] = l;
  }
  __syncthreads();
#pragma unroll
  for (int p = 0; p < 4; p++) {
    int r = (p << 4) + (tid >> 4);      // dst row = src col
    int c = (tid & 15) << 2;
    size_t o = (size_t)(c0 + r) * Cc + r0 + c;
    *(uint2*)&dst[o] = uint2{(unsigned)th[r][c] | ((unsigned)th[r][c+1] << 16),
                             (unsigned)th[r][c+2] | ((unsigned)th[r][c+3] << 16)};
    *(uint2*)&dst[o + pstride] = uint2{(unsigned)tm[r][c] | ((unsigned)tm[r][c+1] << 16),
                                       (unsigned)tm[r][c+2] | ((unsigned)tm[r][c+3] << 16)};
    if (npl == 3)
      *(uint2*)&dst[o + 2 * pstride] = uint2{(unsigned)tl[r][c] | ((unsigned)tl[r][c+1] << 16),
                                             (unsigned)tl[r][c+2] | ((unsigned)tl[r][c+3] << 16)};
  }
}

// Plain split, npl planes
__global__ __launch_bounds__(256) void split_k(const float* __restrict__ src, unsigned short* __restrict__ dst,
                                               long pstride, int npl) {
  int id = blockIdx.x * 256 + threadIdx.x;
  int c = id << 2;
  float4 v = *(const float4*)&src[c];
  unsigned short h[4], m[4], l[4];
  split3(v.x, h[0], m[0], l[0]); split3(v.y, h[1], m[1], l[1]);
  split3(v.z, h[2], m[2], l[2]); split3(v.w, h[3], m[3], l[3]);
  *(uint2*)&dst[c] = uint2{(unsigned)h[0] | ((unsigned)h[1] << 16), (unsigned)h[2] | ((unsigned)h[3] << 16)};
  *(uint2*)&dst[c + pstride] = uint2{(unsigned)m[0] | ((unsigned)m[1] << 16), (unsigned)m[2] | ((unsigned)m[3] << 16)};
  if (npl == 3)
    *(uint2*)&dst[c + 2 * pstride] = uint2{(unsigned)l[0] | ((unsigned)l[1] << 16), (unsigned)l[2] | ((unsigned)l[3] << 16)};
}

// Multi-plane split GEMM body: C = scale * A @ B^T with A,B as NPL bf16 planes.
// NT=6: products hh,hm,mh,hl,lh,mm (error ~2^-24). NT=3: hh,hm,mh (~2^-16).
// 64x64 tile, BK=32, 4 waves of 32x32. global_load_lds width-16 staging,
// double-buffered (T3 minimum 2-phase).
template<int NT, int SPLIT_OUT>
__device__ __forceinline__ void gemm3_body(const unsigned short* __restrict__ Ap, long apl,
                                           const unsigned short* __restrict__ Bp, long bpl,
                                           float* __restrict__ C,
                                           unsigned short* __restrict__ Cs, long cpl,
                                           float scale) {
  constexpr int NPL = (NT == 6) ? 3 : 2;
  constexpr int BUFS = 2 * NPL * 2048;              // shorts per buffer
  __shared__ unsigned short LDS[2 * BUFS];          // double-buffered A+B planes
  const int tid = threadIdx.x, lane = tid & 63, wid = tid >> 6;
  const int m0 = blockIdx.y << 6, n0 = blockIdx.x << 6;

  const unsigned short* sp[2 * NPL];
  int dof[2 * NPL];                                  // byte offset within a buffer
#pragma unroll
  for (int i = 0; i < 2 * NPL; i++) {
    int s = wid * 2 * NPL + i;           // [0, 8*NPL)
    int tile = s >> 2;                   // [0, 2*NPL)
    int ci = ((s & 3) << 6) | lane;      // chunk in tile [0,256)
    int row = ci >> 2;
    int q = (ci & 3) ^ ((row >> 1) & 3); // source chunk for swizzled slot
    int isB = tile >= NPL;
    int pl = isB ? tile - NPL : tile;
    const unsigned short* base = isB ? (Bp + (size_t)pl * bpl) : (Ap + (size_t)pl * apl);
    int r0 = isB ? n0 : m0;
    sp[i] = base + (size_t)(r0 + row) * Cc + (q << 3);
    dof[i] = (tile * 2048 + ((s & 3) << 9)) * 2;
  }

  const int wm = (wid >> 1) << 5, wn = (wid & 1) << 5;
  const int lm = lane & 15, lq = lane >> 4;
  constexpr int PA[6] = {0, 0, 1, 0, 2, 1};
  constexpr int PB[6] = {0, 1, 0, 2, 0, 1};
  const f32x4 zero = {0.f, 0.f, 0.f, 0.f};
  f32x4 acc[2][2] = {{zero, zero}, {zero, zero}};

  // prologue: stage K-tile 0 into buf 0
#pragma unroll
  for (int i = 0; i < 2 * NPL; i++) {
    __builtin_amdgcn_global_load_lds((as1_cvp)sp[i], (as3_vp)((char*)LDS + dof[i]), 16, 0, 0);
    sp[i] += 32;
  }
  __syncthreads();

  int cur = 0;
  for (int k0 = 0; k0 < Cc; k0 += 32) {
    if (k0 + 32 < Cc) {                  // issue next tile's loads (prefetch)
      const int nb = (cur ^ 1) * (BUFS * 2);
#pragma unroll
      for (int i = 0; i < 2 * NPL; i++) {
        __builtin_amdgcn_global_load_lds((as1_cvp)sp[i], (as3_vp)((char*)LDS + nb + dof[i]), 16, 0, 0);
        sp[i] += 32;
      }
    }
    const int cb = cur * BUFS;           // shorts
    short8 af[2][NPL], bf[2][NPL];
#pragma unroll
    for (int i = 0; i < 2; i++)
#pragma unroll
      for (int p = 0; p < NPL; p++) {
        af[i][p] = *(const short8*)&LDS[cb + p * 2048 + sw32(wm + (i << 4) + lm, lq)];
        bf[i][p] = *(const short8*)&LDS[cb + (NPL + p) * 2048 + sw32(wn + (i << 4) + lm, lq)];
      }
#pragma unroll
    for (int i = 0; i < 2; i++)
#pragma unroll
      for (int j = 0; j < 2; j++)
#pragma unroll
        for (int t = 0; t < NT; t++)
          acc[i][j] = __builtin_amdgcn_mfma_f32_16x16x32_bf16(af[i][PA[t]], bf[j][PB[t]], acc[i][j], 0, 0, 0);
    __syncthreads();                     // drains vmcnt(0): next buf staged
    cur ^= 1;
  }
  // C/D: col = lane&15, row = (lane>>4)*4 + reg  [m89-verified]
#pragma unroll
  for (int i = 0; i < 2; i++)
#pragma unroll
    for (int j = 0; j < 2; j++)
#pragma unroll
      for (int r = 0; r < 4; r++) {
        int gr = m0 + wm + (i << 4) + (lq << 2) + r;
        int gc = n0 + wn + (j << 4) + lm;
        size_t o = (size_t)gr * Cc + gc;
        float v = acc[i][j][r] * scale;
        if (SPLIT_OUT) {
          unsigned short h = f2bf(v);
          float rr = v - bf2f(h);
          unsigned short mm2 = f2bf(rr);
          Cs[o] = h;
          Cs[o + cpl] = mm2;
          if (NPL == 3) Cs[o + 2 * (size_t)cpl] = f2bf(rr - bf2f(mm2));
        } else {
          C[o] = v;
        }
      }
}

// Concrete wrappers (no template __global__ — see round-5 link failure)
__global__ __launch_bounds__(256) void gemm3_61_k(const unsigned short* __restrict__ Ap, long apl,
                                                  const unsigned short* __restrict__ Bp, long bpl,
                                                  unsigned short* __restrict__ Cs, long cpl, float scale) {
  gemm3_body<6, 1>(Ap, apl, Bp, bpl, nullptr, Cs, cpl, scale);
}
__global__ __launch_bounds__(256) void gemm3_31_k(const unsigned short* __restrict__ Ap, long apl,
                                                  const unsigned short* __restrict__ Bp, long bpl,
                                                  unsigned short* __restrict__ Cs, long cpl, float scale) {
  gemm3_body<3, 1>(Ap, apl, Bp, bpl, nullptr, Cs, cpl, scale);
}
__global__ __launch_bounds__(256) void gemm3_30_k(const unsigned short* __restrict__ Ap, long apl,
                                                  const unsigned short* __restrict__ Bp, long bpl,
                                                  float* __restrict__ C, float scale) {
  gemm3_body<3, 0>(Ap, apl, Bp, bpl, C, nullptr, 0, scale);
}

// Fused scores + top-8 + softmax. 64 t-rows x 256 slots per block, 512 thr
// (8 waves of 32x64 output). Round-2 geometry, but kq is NOT staged in LDS:
// kq (1.5 MB/batch, pinned to one XCD's L2 by b=bid&7) is read as B-fragments
// DIRECTLY from global (each lane a contiguous 16B short8 at row*1024+k0+lq*8)
// — Common-mistake #7: staging L2-resident data is pure overhead. This removes
// the per-step vmcnt-drain coupling of 48 KB staging to the barrier, 96 KB/step
// of B ds_reads, and 96 KB of LDS. LDS now holds only the split3 x-planes
// (dbuf 2x13.5 KB) and, after the K-loop, the 64x260 f32 score tile (union).
__global__ __launch_bounds__(512, 2) void scores_topk_k(const float* __restrict__ x,
                                                        const unsigned short* __restrict__ kqp,
                                                        float* __restrict__ topw, int* __restrict__ topi) {
  __shared__ __align__(16) char smem[66560];
  unsigned short* lds16 = (unsigned short*)smem;
  float* sc = (float*)smem;                         // tail: 64x260 fp32 (aliases x planes)

  const int tid = threadIdx.x, lane = tid & 63, wid = tid >> 6;
  const int bid = blockIdx.x;
  const int b = bid & 7, tt = bid >> 3;

  const int spr = tid >> 3, spk = (tid & 7) << 2;   // x-tile: row, col(4 floats)
  const float* xsrc = x + ((size_t)b * Tt + (size_t)tt * 64 + spr) * Cc + spk;

  const int wm = (wid & 1) << 5;         // row group (2 x 32 rows)
  const int wn = (wid >> 1) << 6;        // col group (4 x 64 slots)
  const int lm = lane & 15, lq = lane >> 4;

  // B-frag global base: plane p, row b*256 + wn + j*16 + lm, cols k0 + lq*8
  const long KPL = 2048l * 1024;         // kq plane stride (shorts)
  const unsigned short* kqb = kqp + ((size_t)b * Ss + wn + lm) * Cc + (lq << 3);

  constexpr int PA[6] = {0, 0, 1, 0, 2, 1};
  constexpr int PB[6] = {0, 1, 0, 2, 0, 1};
  const f32x4 zero = {0.f, 0.f, 0.f, 0.f};
  f32x4 acc[2][4];
#pragma unroll
  for (int i = 0; i < 2; i++)
#pragma unroll
    for (int j = 0; j < 4; j++) acc[i][j] = zero;

  // ---- prologue: x tile 0 -> regs -> split3 -> planes buf0
  {
    float4 xv = *(const float4*)xsrc; xsrc += 32;
    unsigned short h[4], m[4], l[4];
    split3(xv.x, h[0], m[0], l[0]); split3(xv.y, h[1], m[1], l[1]);
    split3(xv.z, h[2], m[2], l[2]); split3(xv.w, h[3], m[3], l[3]);
    int o = spr * 36 + spk;
    *(uint2*)&lds16[o]        = uint2{(unsigned)h[0] | ((unsigned)h[1] << 16), (unsigned)h[2] | ((unsigned)h[3] << 16)};
    *(uint2*)&lds16[o + 2304] = uint2{(unsigned)m[0] | ((unsigned)m[1] << 16), (unsigned)m[2] | ((unsigned)m[3] << 16)};
    *(uint2*)&lds16[o + 4608] = uint2{(unsigned)l[0] | ((unsigned)l[1] << 16), (unsigned)l[2] | ((unsigned)l[3] << 16)};
  }
  __syncthreads();

  int cur = 0;
  for (int ks = 0; ks < 32; ks++) {
    const int nb = cur ^ 1;
    const int k0 = ks << 5;
    float4 xv2;
    if (ks < 31) { xv2 = *(const float4*)xsrc; xsrc += 32; }
    // ---- B fragments straight from global (L2-resident kq)
    short8 bfr[4][3];
#pragma unroll
    for (int j = 0; j < 4; j++)
#pragma unroll
      for (int p = 0; p < 3; p++)
        bfr[j][p] = *(const short8*)(kqb + (size_t)p * KPL + (size_t)(j << 4) * Cc + k0);
    // ---- A fragments from LDS x-planes (buf cur)
    const int xb = cur * 6912;           // shorts
    short8 afr[2][3];
#pragma unroll
    for (int i = 0; i < 2; i++)
#pragma unroll
      for (int p = 0; p < 3; p++)
        afr[i][p] = *(const short8*)&lds16[xb + p * 2304 + (wm + (i << 4) + lm) * 36 + (lq << 3)];
#pragma unroll
    for (int i = 0; i < 2; i++)
#pragma unroll
      for (int j = 0; j < 4; j++)
#pragma unroll
        for (int t = 0; t < 6; t++)
          acc[i][j] = __builtin_amdgcn_mfma_f32_16x16x32_bf16(afr[i][PA[t]], bfr[j][PB[t]], acc[i][j], 0, 0, 0);
    // ---- split next x tile into planes buf nb (write-late; regs only)
    if (ks < 31) {
      unsigned short h[4], m[4], l[4];
      split3(xv2.x, h[0], m[0], l[0]); split3(xv2.y, h[1], m[1], l[1]);
      split3(xv2.z, h[2], m[2], l[2]); split3(xv2.w, h[3], m[3], l[3]);
      int o = nb * 6912 + spr * 36 + spk;
      *(uint2*)&lds16[o]        = uint2{(unsigned)h[0] | ((unsigned)h[1] << 16), (unsigned)h[2] | ((unsigned)h[3] << 16)};
      *(uint2*)&lds16[o + 2304] = uint2{(unsigned)m[0] | ((unsigned)m[1] << 16), (unsigned)m[2] | ((unsigned)m[3] << 16)};
      *(uint2*)&lds16[o + 4608] = uint2{(unsigned)l[0] | ((unsigned)l[1] << 16), (unsigned)l[2] | ((unsigned)l[3] << 16)};
    }
    __syncthreads();                     // orders x-plane buffer flip (lgkm only)
    cur ^= 1;
  }

  // scores -> LDS (scaled 1/32), then per-wave top-8 + softmax
#pragma unroll
  for (int i = 0; i < 2; i++)
#pragma unroll
    for (int j = 0; j < 4; j++)
#pragma unroll
      for (int r = 0; r < 4; r++)
        sc[(wm + (i << 4) + (lq << 2) + r) * 260 + wn + (j << 4) + lm] = acc[i][j][r] * 0.03125f;
  __syncthreads();

  for (int r2 = 0; r2 < 8; r2++) {
    int row = (wid << 3) + r2;
    float4 v = *(const float4*)(sc + row * 260 + (lane << 2));
    float cand[4] = {v.x, v.y, v.z, v.w};
    float topv[8]; int tops[8];
#pragma unroll
    for (int k = 0; k < 8; k++) {
      float bv = -1e30f; int bs = 1 << 20;
#pragma unroll
      for (int e = 0; e < 4; e++) {
        int s = (lane << 2) + e;
        if (cand[e] > bv || (cand[e] == bv && s < bs)) { bv = cand[e]; bs = s; }
      }
#pragma unroll
      for (int m = 32; m >= 1; m >>= 1) {
        float ov = __shfl_xor(bv, m, 64);
        int   os = __shfl_xor(bs, m, 64);
        if (ov > bv || (ov == bv && os < bs)) { bv = ov; bs = os; }
      }
      topv[k] = bv; tops[k] = bs;
      if ((bs >> 2) == lane) cand[bs & 3] = -1e30f;
    }
    float mx = topv[0];
    float sum = 0.f;
#pragma unroll
    for (int k = 0; k < 8; k++) sum += expf(topv[k] - mx);
    if (lane < 8) {
      float myv = topv[0]; int myi = tops[0];
#pragma unroll
      for (int k = 1; k < 8; k++) if (lane == k) { myv = topv[k]; myi = tops[k]; }
      size_t trow = (size_t)b * Tt + (size_t)tt * 64 + row;
      topw[trow * 8 + lane] = expf(myv - mx) / sum;
      topi[trow * 8 + lane] = myi;
    }
  }
}

// out[row,:] = 0.5 * sum_k w_k * u[b*256+idx_k, :]   (fp32)
__global__ __launch_bounds__(256) void gatherout_k(const float* __restrict__ u, const float* __restrict__ topw,
                                                   const int* __restrict__ topi, float* __restrict__ out) {
  __shared__ float w[8];
  __shared__ int  id8[8];
  const int row = blockIdx.x;
  const int b = row >> 11;
  if (threadIdx.x < 8) {
    w[threadIdx.x]   = topw[(size_t)row * 8 + threadIdx.x];
    id8[threadIdx.x] = topi[(size_t)row * 8 + threadIdx.x];
  }
  __syncthreads();
  int c = threadIdx.x << 2;
  float ax = 0.f, ay = 0.f, az = 0.f, aw = 0.f;
#pragma unroll
  for (int j = 0; j < 8; j++) {
    const float4 vv = *(const float4*)&u[((size_t)(b << 8) + id8[j]) * Cc + c];
    float wj = w[j];
    ax = fmaf(wj, vv.x, ax); ay = fmaf(wj, vv.y, ay);
    az = fmaf(wj, vv.z, az); aw = fmaf(wj, vv.w, aw);
  }
  *(float4*)&out[(size_t)row * Cc + c] = make_float4(ax * 0.5f, ay * 0.5f, az * 0.5f, aw * 0.5f);
}

extern "C" void kernel_launch(void* const* d_in, const int* in_sizes, int n_in,
                              void* d_out, int out_size, void* d_ws, size_t ws_size,
                              hipStream_t stream) {
  (void)in_sizes; (void)n_in; (void)out_size; (void)ws_size;
  const float* x  = (const float*)d_in[0];
  const float* Wq = (const float*)d_in[1];
  const float* Wk = (const float*)d_in[2];
  const float* Wv = (const float*)d_in[3];
  const float* Wp = (const float*)d_in[4];
  float* out = (float*)d_out;

  char* ws = (char*)d_ws;
  const size_t MB = 1ull << 20;
  const long PS1 = 1024l * 1024;   // plane stride, 1024x1024 (shorts)
  const long PS2 = 2048l * 1024;   // plane stride, 2048x1024 (shorts)
  unsigned short* slotp = (unsigned short*)(ws + 0 * MB);   // 12 MB: 3 planes [2048x1024]
  unsigned short* Wqt   = (unsigned short*)(ws + 12 * MB);  // 6 MB: 3 planes [c][d]
  unsigned short* Wkt   = (unsigned short*)(ws + 18 * MB);  // 6 MB: 3 planes [e][d]
  unsigned short* Wvt   = (unsigned short*)(ws + 24 * MB);  // 4 MB: 2 planes [e][d]
  unsigned short* Wpp   = (unsigned short*)(ws + 28 * MB);  // 4 MB: 2 planes [o][d]
  unsigned short* MtT   = (unsigned short*)(ws + 32 * MB);  // 6 MB: 3 planes [c][e] = (Wk^T Wq)^T
  unsigned short* kqp   = (unsigned short*)(ws + 38 * MB);  // 12 MB: 3 planes [2048x1024]
  unsigned short* W2p   = (unsigned short*)(ws + 50 * MB);  // 4 MB: 2 planes [o][e] = Wp@Wv
  float*          u     = (float*)(ws + 54 * MB);           // 8 MB fp32 [2048x1024]
  float*          topw  = (float*)(ws + 62 * MB);           // 0.5 MB
  int*            topi  = (int*)(ws + 62 * MB + 512 * 1024);// 0.5 MB -> 63 MB total (<=113 validated)

  // 1. pool + split3 slots (x read once here)
  poolsplit_k<<<2048, 256, 0, stream>>>(x, slotp);
  // 2. transpose+split weights
  split_t_k<<<dim3(16, 16), 256, 0, stream>>>(Wq, Wqt, PS1, 3);
  split_t_k<<<dim3(16, 16), 256, 0, stream>>>(Wk, Wkt, PS1, 3);
  split_t_k<<<dim3(16, 16), 256, 0, stream>>>(Wv, Wvt, PS1, 2);
  split_k<<<1024, 256, 0, stream>>>(Wp, Wpp, PS1, 2);
  // 3. MtT[c][e] = sum_d Wq[d][c]*Wk[d][e]   (6-product, split3 out)
  gemm3_61_k<<<dim3(16, 16), 256, 0, stream>>>(Wqt, PS1, Wkt, PS1, MtT, PS1, 1.0f);
  // 4. kq[s][c] = sum_e slots[s][e]*MtT[c][e] (6-product, split3 out)
  gemm3_61_k<<<dim3(16, 32), 256, 0, stream>>>(slotp, PS2, MtT, PS1, kqp, PS2, 1.0f);
  // 5. W2[o][e] = sum_d Wp[o][d]*Wvt[e][d]    (3-product, split2 out)
  gemm3_31_k<<<dim3(16, 16), 256, 0, stream>>>(Wpp, PS1, Wvt, PS1, W2p, PS1, 1.0f);
  // 6. u[s][o] = sum_e slots[s][e]*W2[o][e]   (3-product, fp32 out)
  gemm3_30_k<<<dim3(16, 32), 256, 0, stream>>>(slotp, PS2, W2p, PS1, u, 1.0f);
  // 7. fused scores (6-product, B direct from L2, no kq staging) + top-8 + softmax
  scores_topk_k<<<256, 512, 0, stream>>>(x, kqp, topw, topi);
  // 8. gather + 0.5 scale
  gatherout_k<<<16384, 256, 0, stream>>>(u, topw, topi, out);
}

// Round 5
// 361.878 us; speedup vs baseline: 1.1568x; 1.1181x over previous
//
#include <hip/hip_runtime.h>
#include <cstdint>
#include <cstddef>

#define Tt 2048
#define Cc 1024
#define Ss 256

using short8 = __attribute__((ext_vector_type(8))) short;
using f32x4  = __attribute__((ext_vector_type(4))) float;
typedef const __attribute__((address_space(1))) void* as1_cvp;
typedef __attribute__((address_space(3))) void* as3_vp;

__device__ __forceinline__ unsigned short f2bf(float f) {
  unsigned int u = __float_as_uint(f);
  u += 0x7fffu + ((u >> 16) & 1u);
  return (unsigned short)(u >> 16);
}
__device__ __forceinline__ float bf2f(unsigned short h) {
  return __uint_as_float(((unsigned)h) << 16);
}
// 3-way split: v = h + m + l to ~2^-24 relative
__device__ __forceinline__ void split3(float v, unsigned short& h, unsigned short& m, unsigned short& l) {
  h = f2bf(v);
  float r = v - bf2f(h);
  m = f2bf(r);
  l = f2bf(r - bf2f(m));
}

// LDS short-offset for N-row x 32-short tile, chunk-XOR swizzled (2-way bank
// aliasing on ds_read_b128 = free, m136)
__device__ __forceinline__ int sw32(int row, int q) {
  return row * 32 + ((q ^ ((row >> 1) & 3)) << 3);
}

// slots planes = split3(mean over 8 consecutive t rows)
__global__ __launch_bounds__(256) void poolsplit_k(const float* __restrict__ x, unsigned short* __restrict__ sp) {
  const long PS2 = 2048l * 1024;
  const int sli = blockIdx.x;           // b*256+s
  const int c = threadIdx.x << 2;
  const float* src = x + (size_t)sli * 8 * Cc + c;
  float a[4] = {0.f, 0.f, 0.f, 0.f};
#pragma unroll
  for (int j = 0; j < 8; j++) {
    float4 v = *(const float4*)(src + (size_t)j * Cc);
    a[0] += v.x; a[1] += v.y; a[2] += v.z; a[3] += v.w;
  }
  unsigned short h[4], m[4], l[4];
#pragma unroll
  for (int e = 0; e < 4; e++) split3(a[e] * 0.125f, h[e], m[e], l[e]);
  size_t o = (size_t)sli * Cc + c;
  *(uint2*)&sp[o]           = uint2{(unsigned)h[0] | ((unsigned)h[1] << 16), (unsigned)h[2] | ((unsigned)h[3] << 16)};
  *(uint2*)&sp[o + PS2]     = uint2{(unsigned)m[0] | ((unsigned)m[1] << 16), (unsigned)m[2] | ((unsigned)m[3] << 16)};
  *(uint2*)&sp[o + 2 * PS2] = uint2{(unsigned)l[0] | ((unsigned)l[1] << 16), (unsigned)l[2] | ((unsigned)l[3] << 16)};
}

// Transpose + split: dst[p][e][d] = split3(src[d][e]), npl planes written.
__global__ __launch_bounds__(256) void split_t_k(const float* __restrict__ src, unsigned short* __restrict__ dst,
                                                 long pstride, int npl) {
  __shared__ unsigned short th[64][68], tm[64][68], tl[64][68];
  const int r0 = blockIdx.y << 6, c0 = blockIdx.x << 6;
  const int tid = threadIdx.x;
#pragma unroll
  for (int p = 0; p < 4; p++) {
    int r = (p << 4) + (tid >> 4);
    int c = (tid & 15) << 2;
    float4 v = *(const float4*)&src[(size_t)(r0 + r) * Cc + c0 + c];
    unsigned short h, m, l;
    split3(v.x, h, m, l); th[c + 0][r] = h; tm[c + 0][r] = m; tl[c + 0][r] = l;
    split3(v.y, h, m, l); th[c + 1][r] = h; tm[c + 1][r] = m; tl[c + 1][r] = l;
    split3(v.z, h, m, l); th[c + 2][r] = h; tm[c + 2][r] = m; tl[c + 2][r] = l;
    split3(v.w, h, m, l); th[c + 3][r] = h; tm[c + 3][r] = m; tl[c + 3][r] = l;
  }
  __syncthreads();
#pragma unroll
  for (int p = 0; p < 4; p++) {
    int r = (p << 4) + (tid >> 4);      // dst row = src col
    int c = (tid & 15) << 2;
    size_t o = (size_t)(c0 + r) * Cc + r0 + c;
    *(uint2*)&dst[o] = uint2{(unsigned)th[r][c] | ((unsigned)th[r][c+1] << 16),
                             (unsigned)th[r][c+2] | ((unsigned)th[r][c+3] << 16)};
    *(uint2*)&dst[o + pstride] = uint2{(unsigned)tm[r][c] | ((unsigned)tm[r][c+1] << 16),
                                       (unsigned)tm[r][c+2] | ((unsigned)tm[r][c+3] << 16)};
    if (npl == 3)
      *(uint2*)&dst[o + 2 * pstride] = uint2{(unsigned)tl[r][c] | ((unsigned)tl[r][c+1] << 16),
                                             (unsigned)tl[r][c+2] | ((unsigned)tl[r][c+3] << 16)};
  }
}

// Plain split, npl planes
__global__ __launch_bounds__(256) void split_k(const float* __restrict__ src, unsigned short* __restrict__ dst,
                                               long pstride, int npl) {
  int id = blockIdx.x * 256 + threadIdx.x;
  int c = id << 2;
  float4 v = *(const float4*)&src[c];
  unsigned short h[4], m[4], l[4];
  split3(v.x, h[0], m[0], l[0]); split3(v.y, h[1], m[1], l[1]);
  split3(v.z, h[2], m[2], l[2]); split3(v.w, h[3], m[3], l[3]);
  *(uint2*)&dst[c] = uint2{(unsigned)h[0] | ((unsigned)h[1] << 16), (unsigned)h[2] | ((unsigned)h[3] << 16)};
  *(uint2*)&dst[c + pstride] = uint2{(unsigned)m[0] | ((unsigned)m[1] << 16), (unsigned)m[2] | ((unsigned)m[3] << 16)};
  if (npl == 3)
    *(uint2*)&dst[c + 2 * pstride] = uint2{(unsigned)l[0] | ((unsigned)l[1] << 16), (unsigned)l[2] | ((unsigned)l[3] << 16)};
}

// Multi-plane split GEMM body, 64x64 tile, BK=32, 4 waves of 32x32.
// NT=6: hh,hm,mh,hl,lh,mm (~2^-24). NT=3: hh,hm,mh (~2^-16).
// dbuf width-16 global_load_lds staging. LDS passed in (kernel-scope) so
// z-fused kernels share one buffer across template instantiations.
template<int NT, int SPLIT_OUT>
__device__ __forceinline__ void gemm3_body(unsigned short* LDS,
                                           const unsigned short* __restrict__ Ap, long apl,
                                           const unsigned short* __restrict__ Bp, long bpl,
                                           float* __restrict__ C,
                                           unsigned short* __restrict__ Cs, long cpl,
                                           float scale) {
  constexpr int NPL = (NT == 6) ? 3 : 2;
  constexpr int BUFS = 2 * NPL * 2048;              // shorts per buffer
  const int tid = threadIdx.x, lane = tid & 63, wid = tid >> 6;
  const int m0 = blockIdx.y << 6, n0 = blockIdx.x << 6;

  const unsigned short* sp[2 * NPL];
  int dof[2 * NPL];                                  // byte offset within a buffer
#pragma unroll
  for (int i = 0; i < 2 * NPL; i++) {
    int s = wid * 2 * NPL + i;           // [0, 8*NPL)
    int tile = s >> 2;                   // [0, 2*NPL)
    int ci = ((s & 3) << 6) | lane;      // chunk in tile [0,256)
    int row = ci >> 2;
    int q = (ci & 3) ^ ((row >> 1) & 3); // source chunk for swizzled slot
    int isB = tile >= NPL;
    int pl = isB ? tile - NPL : tile;
    const unsigned short* base = isB ? (Bp + (size_t)pl * bpl) : (Ap + (size_t)pl * apl);
    int r0 = isB ? n0 : m0;
    sp[i] = base + (size_t)(r0 + row) * Cc + (q << 3);
    dof[i] = (tile * 2048 + ((s & 3) << 9)) * 2;
  }

  const int wm = (wid >> 1) << 5, wn = (wid & 1) << 5;
  const int lm = lane & 15, lq = lane >> 4;
  constexpr int PA[6] = {0, 0, 1, 0, 2, 1};
  constexpr int PB[6] = {0, 1, 0, 2, 0, 1};
  const f32x4 zero = {0.f, 0.f, 0.f, 0.f};
  f32x4 acc[2][2] = {{zero, zero}, {zero, zero}};

  // prologue: stage K-tile 0 into buf 0
#pragma unroll
  for (int i = 0; i < 2 * NPL; i++) {
    __builtin_amdgcn_global_load_lds((as1_cvp)sp[i], (as3_vp)((char*)LDS + dof[i]), 16, 0, 0);
    sp[i] += 32;
  }
  __syncthreads();

  int cur = 0;
  for (int k0 = 0; k0 < Cc; k0 += 32) {
    if (k0 + 32 < Cc) {                  // issue next tile's loads (prefetch)
      const int nb = (cur ^ 1) * (BUFS * 2);
#pragma unroll
      for (int i = 0; i < 2 * NPL; i++) {
        __builtin_amdgcn_global_load_lds((as1_cvp)sp[i], (as3_vp)((char*)LDS + nb + dof[i]), 16, 0, 0);
        sp[i] += 32;
      }
    }
    const int cb = cur * BUFS;           // shorts
    short8 af[2][NPL], bf[2][NPL];
#pragma unroll
    for (int i = 0; i < 2; i++)
#pragma unroll
      for (int p = 0; p < NPL; p++) {
        af[i][p] = *(const short8*)&LDS[cb + p * 2048 + sw32(wm + (i << 4) + lm, lq)];
        bf[i][p] = *(const short8*)&LDS[cb + (NPL + p) * 2048 + sw32(wn + (i << 4) + lm, lq)];
      }
#pragma unroll
    for (int i = 0; i < 2; i++)
#pragma unroll
      for (int j = 0; j < 2; j++)
#pragma unroll
        for (int t = 0; t < NT; t++)
          acc[i][j] = __builtin_amdgcn_mfma_f32_16x16x32_bf16(af[i][PA[t]], bf[j][PB[t]], acc[i][j], 0, 0, 0);
    __syncthreads();                     // drains vmcnt(0): next buf staged
    cur ^= 1;
  }
  // C/D: col = lane&15, row = (lane>>4)*4 + reg  [m89-verified]
#pragma unroll
  for (int i = 0; i < 2; i++)
#pragma unroll
    for (int j = 0; j < 2; j++)
#pragma unroll
      for (int r = 0; r < 4; r++) {
        int gr = m0 + wm + (i << 4) + (lq << 2) + r;
        int gc = n0 + wn + (j << 4) + lm;
        size_t o = (size_t)gr * Cc + gc;
        float v = acc[i][j][r] * scale;
        if (SPLIT_OUT) {
          unsigned short h = f2bf(v);
          float rr = v - bf2f(h);
          unsigned short mm2 = f2bf(rr);
          Cs[o] = h;
          Cs[o + cpl] = mm2;
          if (NPL == 3) Cs[o + 2 * (size_t)cpl] = f2bf(rr - bf2f(mm2));
        } else {
          C[o] = v;
        }
      }
}

// m97-structure body: 128x128 tile, BK=32, 4 waves each 64x64 (acc[4][4]).
// dbuf width-16 global_load_lds staging of NPL A-planes + NPL B-planes.
template<int NT, int SPLIT_OUT>
__device__ __forceinline__ void gemm128_body(unsigned short* LDS,
                                             const unsigned short* __restrict__ Ap, long apl,
                                             const unsigned short* __restrict__ Bp, long bpl,
                                             float* __restrict__ C,
                                             unsigned short* __restrict__ Cs, long cpl,
                                             float scale) {
  constexpr int NPL = (NT == 6) ? 3 : 2;
  constexpr int BUFS = 2 * NPL * 4096;              // shorts per buffer (tile = 128x32)
  const int tid = threadIdx.x, lane = tid & 63, wid = tid >> 6;
  const int m0 = blockIdx.y << 7, n0 = blockIdx.x << 7;

  // staging: 2*NPL tiles x 8 chunks of 1KB; 4*NPL chunks per wave
  const unsigned short* sp[4 * NPL];
  int dof[4 * NPL];
#pragma unroll
  for (int i = 0; i < 4 * NPL; i++) {
    int s = wid * 4 * NPL + i;           // [0, 16*NPL)
    int tile = s >> 3;                   // [0, 2*NPL)
    int ci = ((s & 7) << 6) | lane;      // [0,512) position in tile
    int row = ci >> 2;                   // [0,128)
    int q = (ci & 3) ^ ((row >> 1) & 3);
    int isB = tile >= NPL;
    int pl = isB ? tile - NPL : tile;
    const unsigned short* base = isB ? (Bp + (size_t)pl * bpl) : (Ap + (size_t)pl * apl);
    int r0 = isB ? n0 : m0;
    sp[i] = base + (size_t)(r0 + row) * Cc + (q << 3);
    dof[i] = (tile * 4096 + ((s & 7) << 9)) * 2;
  }

  const int wr = (wid >> 1) << 6, wc = (wid & 1) << 6;
  const int lm = lane & 15, lq = lane >> 4;
  constexpr int PA[6] = {0, 0, 1, 0, 2, 1};
  constexpr int PB[6] = {0, 1, 0, 2, 0, 1};
  const f32x4 zero = {0.f, 0.f, 0.f, 0.f};
  f32x4 acc[4][4];
#pragma unroll
  for (int i = 0; i < 4; i++)
#pragma unroll
    for (int j = 0; j < 4; j++) acc[i][j] = zero;

  // prologue: stage K-tile 0 into buf 0
#pragma unroll
  for (int i = 0; i < 4 * NPL; i++) {
    __builtin_amdgcn_global_load_lds((as1_cvp)sp[i], (as3_vp)((char*)LDS + dof[i]), 16, 0, 0);
    sp[i] += 32;
  }
  __syncthreads();

  int cur = 0;
  for (int k0 = 0; k0 < Cc; k0 += 32) {
    if (k0 + 32 < Cc) {                  // prefetch next tile
      const int nb = (cur ^ 1) * (BUFS * 2);
#pragma unroll
      for (int i = 0; i < 4 * NPL; i++) {
        __builtin_amdgcn_global_load_lds((as1_cvp)sp[i], (as3_vp)((char*)LDS + nb + dof[i]), 16, 0, 0);
        sp[i] += 32;
      }
    }
    const int cb = cur * BUFS;           // shorts
    short8 af[4][NPL];
#pragma unroll
    for (int i = 0; i < 4; i++)
#pragma unroll
      for (int p = 0; p < NPL; p++)
        af[i][p] = *(const short8*)&LDS[cb + p * 4096 + sw32(wr + (i << 4) + lm, lq)];
#pragma unroll
    for (int j = 0; j < 4; j++) {
      short8 bf[NPL];
#pragma unroll
      for (int p = 0; p < NPL; p++)
        bf[p] = *(const short8*)&LDS[cb + (NPL + p) * 4096 + sw32(wc + (j << 4) + lm, lq)];
#pragma unroll
      for (int i = 0; i < 4; i++)
#pragma unroll
        for (int t = 0; t < NT; t++)
          acc[i][j] = __builtin_amdgcn_mfma_f32_16x16x32_bf16(af[i][PA[t]], bf[PB[t]], acc[i][j], 0, 0, 0);
    }
    __syncthreads();
    cur ^= 1;
  }
  // epilogue
#pragma unroll
  for (int i = 0; i < 4; i++)
#pragma unroll
    for (int j = 0; j < 4; j++)
#pragma unroll
      for (int r = 0; r < 4; r++) {
        int gr = m0 + wr + (i << 4) + (lq << 2) + r;
        int gc = n0 + wc + (j << 4) + lm;
        size_t o = (size_t)gr * Cc + gc;
        float v = acc[i][j][r] * scale;
        if (SPLIT_OUT) {
          unsigned short h = f2bf(v);
          float rr = v - bf2f(h);
          unsigned short mm2 = f2bf(rr);
          Cs[o] = h;
          Cs[o + cpl] = mm2;
          if (NPL == 3) Cs[o + 2 * (size_t)cpl] = f2bf(rr - bf2f(mm2));
        } else {
          C[o] = v;
        }
      }
}

// steps 3+5 fused (both 1024^2, independent): z=0 MtT (6-prod split3),
// z=1 W2 (3-prod split2). 512 blocks -> 2 blocks/CU (cross-block overlap).
__global__ __launch_bounds__(256) void gemm35_k(const unsigned short* __restrict__ Wqt,
                                                const unsigned short* __restrict__ Wkt,
                                                const unsigned short* __restrict__ Wpp,
                                                const unsigned short* __restrict__ Wvt,
                                                unsigned short* __restrict__ MtT,
                                                unsigned short* __restrict__ W2p, long ps1) {
  __shared__ unsigned short LDS[24576];             // 48 KB = dbuf for NT=6
  if (blockIdx.z == 0)
    gemm3_body<6, 1>(LDS, Wqt, ps1, Wkt, ps1, nullptr, MtT, ps1, 1.0f);
  else
    gemm3_body<3, 1>(LDS, Wpp, ps1, Wvt, ps1, nullptr, W2p, ps1, 1.0f);
}

// steps 4+6 fused (both 2048x1024x1024, share A=slotp): z=0 kq (6-prod split3),
// z=1 u (3-prod fp32). 128^2 tiles, grid (8,16,2)=256 blocks -> full chip.
__global__ __launch_bounds__(256) void gemm46_k(const unsigned short* __restrict__ slotp, long ps2,
                                                const unsigned short* __restrict__ MtT,
                                                const unsigned short* __restrict__ W2p, long ps1,
                                                unsigned short* __restrict__ kqp,
                                                float* __restrict__ u) {
  __shared__ unsigned short LDS[49152];             // 96 KB = dbuf for NT=6 at 128-tile
  if (blockIdx.z == 0)
    gemm128_body<6, 1>(LDS, slotp, ps2, MtT, ps1, nullptr, kqp, ps2, 1.0f);
  else
    gemm128_body<3, 0>(LDS, slotp, ps2, W2p, ps1, u, nullptr, 0, 1.0f);
}

// Fused scores + top-8 + softmax (round-2 version, best measured: 132.8 us).
// 64 t-rows x 256 slots per block, 512 thr. BK=32 dbuf: kq 3 planes via
// global_load_lds (2x24 KB x2), x staged to regs + split3 written late into
// padded LDS planes (2x13.5 KB). One barrier per K-step.
__global__ __launch_bounds__(512) void scores_topk_k(const float* __restrict__ x,
                                                     const unsigned short* __restrict__ kqp,
                                                     float* __restrict__ topw, int* __restrict__ topi) {
  __shared__ __align__(16) char smem[125952];
  unsigned short* lds16 = (unsigned short*)smem;
  float* sc = (float*)smem;                         // tail: 64x260 fp32

  const int tid = threadIdx.x, lane = tid & 63, wid = tid >> 6;
  const int bid = blockIdx.x;
  const int b = bid & 7, tt = bid >> 3;

  // kq staging: 48 slots (3 planes x 16 sub-tiles), 6 per wave
  const char* ksrc[6];
  int kdst[6];                                      // byte offset within a kq buffer
#pragma unroll
  for (int i = 0; i < 6; i++) {
    int s = wid * 6 + i;                 // [0,48)
    int p = s >> 4, sub = s & 15;
    int ci = (sub << 6) | lane;          // [0,1024)
    int row = ci >> 2;
    int q = (ci & 3) ^ ((row >> 1) & 3);
    ksrc[i] = (const char*)(kqp + (size_t)p * (2048l * 1024) + ((size_t)b * Ss + row) * Cc + (q << 3));
    kdst[i] = p * 16384 + sub * 1024;
  }
  const int spr = tid >> 3, spk = (tid & 7) << 2;   // x-tile: row, col(4 floats)
  const float* xsrc = x + ((size_t)b * Tt + (size_t)tt * 64 + spr) * Cc + spk;

  const int wm = (wid & 1) << 5;         // row group
  const int wn = (wid >> 1) << 6;        // col group (x4)
  const int lm = lane & 15, lq = lane >> 4;
  const int XP = 49152;                  // x-plane base (shorts); buf stride 6912, plane stride 2304

  constexpr int PA[6] = {0, 0, 1, 0, 2, 1};
  constexpr int PB[6] = {0, 1, 0, 2, 0, 1};
  const f32x4 zero = {0.f, 0.f, 0.f, 0.f};
  f32x4 acc[2][4];
#pragma unroll
  for (int i = 0; i < 2; i++)
#pragma unroll
    for (int j = 0; j < 4; j++) acc[i][j] = zero;

  // ---- prologue: stage K-tile 0 (x -> regs -> split -> planes buf0; kq -> buf0)
  {
    float4 xv = *(const float4*)xsrc; xsrc += 32;
#pragma unroll
    for (int i = 0; i < 6; i++) {
      __builtin_amdgcn_global_load_lds((as1_cvp)ksrc[i], (as3_vp)(smem + kdst[i]), 16, 0, 0);
      ksrc[i] += 64;
    }
    unsigned short h[4], m[4], l[4];
    split3(xv.x, h[0], m[0], l[0]); split3(xv.y, h[1], m[1], l[1]);
    split3(xv.z, h[2], m[2], l[2]); split3(xv.w, h[3], m[3], l[3]);
    int o = XP + spr * 36 + spk;
    *(uint2*)&lds16[o]        = uint2{(unsigned)h[0] | ((unsigned)h[1] << 16), (unsigned)h[2] | ((unsigned)h[3] << 16)};
    *(uint2*)&lds16[o + 2304] = uint2{(unsigned)m[0] | ((unsigned)m[1] << 16), (unsigned)m[2] | ((unsigned)m[3] << 16)};
    *(uint2*)&lds16[o + 4608] = uint2{(unsigned)l[0] | ((unsigned)l[1] << 16), (unsigned)l[2] | ((unsigned)l[3] << 16)};
  }
  __syncthreads();

  int cur = 0;
  for (int ks = 0; ks < 32; ks++) {
    const int nb = cur ^ 1;
    float4 xv2;
    if (ks < 31) {                       // issue next tile's loads (prefetch)
      xv2 = *(const float4*)xsrc; xsrc += 32;
#pragma unroll
      for (int i = 0; i < 6; i++) {
        __builtin_amdgcn_global_load_lds((as1_cvp)ksrc[i], (as3_vp)(smem + nb * 49152 + kdst[i]), 16, 0, 0);
        ksrc[i] += 64;
      }
    }
    // ---- compute current tile
    const int xb = XP + cur * 6912;      // shorts
    const int kb = cur * 24576;          // shorts
    short8 afr[2][3], bfr[4][3];
#pragma unroll
    for (int i = 0; i < 2; i++)
#pragma unroll
      for (int p = 0; p < 3; p++)
        afr[i][p] = *(const short8*)&lds16[xb + p * 2304 + (wm + (i << 4) + lm) * 36 + (lq << 3)];
#pragma unroll
    for (int j = 0; j < 4; j++) {
      int br = wn + (j << 4) + lm;
      int bo = (br << 5) + ((lq ^ ((br >> 1) & 3)) << 3);
#pragma unroll
      for (int p = 0; p < 3; p++)
        bfr[j][p] = *(const short8*)&lds16[kb + p * 8192 + bo];
    }
#pragma unroll
    for (int i = 0; i < 2; i++)
#pragma unroll
      for (int j = 0; j < 4; j++)
#pragma unroll
        for (int t = 0; t < 6; t++)
          acc[i][j] = __builtin_amdgcn_mfma_f32_16x16x32_bf16(afr[i][PA[t]], bfr[j][PB[t]], acc[i][j], 0, 0, 0);
    // ---- split next x tile into planes buf nb (write-late; regs only)
    if (ks < 31) {
      unsigned short h[4], m[4], l[4];
      split3(xv2.x, h[0], m[0], l[0]); split3(xv2.y, h[1], m[1], l[1]);
      split3(xv2.z, h[2], m[2], l[2]); split3(xv2.w, h[3], m[3], l[3]);
      int o = XP + nb * 6912 + spr * 36 + spk;
      *(uint2*)&lds16[o]        = uint2{(unsigned)h[0] | ((unsigned)h[1] << 16), (unsigned)h[2] | ((unsigned)h[3] << 16)};
      *(uint2*)&lds16[o + 2304] = uint2{(unsigned)m[0] | ((unsigned)m[1] << 16), (unsigned)m[2] | ((unsigned)m[3] << 16)};
      *(uint2*)&lds16[o + 4608] = uint2{(unsigned)l[0] | ((unsigned)l[1] << 16), (unsigned)l[2] | ((unsigned)l[3] << 16)};
    }
    __syncthreads();                     // drains vmcnt(0): kq buf nb staged; plane writes visible
    cur ^= 1;
  }

  // scores -> LDS (scaled 1/32), then per-wave top-8 + softmax
#pragma unroll
  for (int i = 0; i < 2; i++)
#pragma unroll
    for (int j = 0; j < 4; j++)
#pragma unroll
      for (int r = 0; r < 4; r++)
        sc[(wm + (i << 4) + (lq << 2) + r) * 260 + wn + (j << 4) + lm] = acc[i][j][r] * 0.03125f;
  __syncthreads();

  for (int r2 = 0; r2 < 8; r2++) {
    int row = (wid << 3) + r2;
    float4 v = *(const float4*)(sc + row * 260 + (lane << 2));
    float cand[4] = {v.x, v.y, v.z, v.w};
    float topv[8]; int tops[8];
#pragma unroll
    for (int k = 0; k < 8; k++) {
      float bv = -1e30f; int bs = 1 << 20;
#pragma unroll
      for (int e = 0; e < 4; e++) {
        int s = (lane << 2) + e;
        if (cand[e] > bv || (cand[e] == bv && s < bs)) { bv = cand[e]; bs = s; }
      }
#pragma unroll
      for (int m = 32; m >= 1; m >>= 1) {
        float ov = __shfl_xor(bv, m, 64);
        int   os = __shfl_xor(bs, m, 64);
        if (ov > bv || (ov == bv && os < bs)) { bv = ov; bs = os; }
      }
      topv[k] = bv; tops[k] = bs;
      if ((bs >> 2) == lane) cand[bs & 3] = -1e30f;
    }
    float mx = topv[0];
    float sum = 0.f;
#pragma unroll
    for (int k = 0; k < 8; k++) sum += expf(topv[k] - mx);
    if (lane < 8) {
      float myv = topv[0]; int myi = tops[0];
#pragma unroll
      for (int k = 1; k < 8; k++) if (lane == k) { myv = topv[k]; myi = tops[k]; }
      size_t trow = (size_t)b * Tt + (size_t)tt * 64 + row;
      topw[trow * 8 + lane] = expf(myv - mx) / sum;
      topi[trow * 8 + lane] = myi;
    }
  }
}

// out[row,:] = 0.5 * sum_k w_k * u[b*256+idx_k, :]   (fp32)
__global__ __launch_bounds__(256) void gatherout_k(const float* __restrict__ u, const float* __restrict__ topw,
                                                   const int* __restrict__ topi, float* __restrict__ out) {
  __shared__ float w[8];
  __shared__ int  id8[8];
  const int row = blockIdx.x;
  const int b = row >> 11;
  if (threadIdx.x < 8) {
    w[threadIdx.x]   = topw[(size_t)row * 8 + threadIdx.x];
    id8[threadIdx.x] = topi[(size_t)row * 8 + threadIdx.x];
  }
  __syncthreads();
  int c = threadIdx.x << 2;
  float ax = 0.f, ay = 0.f, az = 0.f, aw = 0.f;
#pragma unroll
  for (int j = 0; j < 8; j++) {
    const float4 vv = *(const float4*)&u[((size_t)(b << 8) + id8[j]) * Cc + c];
    float wj = w[j];
    ax = fmaf(wj, vv.x, ax); ay = fmaf(wj, vv.y, ay);
    az = fmaf(wj, vv.z, az); aw = fmaf(wj, vv.w, aw);
  }
  *(float4*)&out[(size_t)row * Cc + c] = make_float4(ax * 0.5f, ay * 0.5f, az * 0.5f, aw * 0.5f);
}

extern "C" void kernel_launch(void* const* d_in, const int* in_sizes, int n_in,
                              void* d_out, int out_size, void* d_ws, size_t ws_size,
                              hipStream_t stream) {
  (void)in_sizes; (void)n_in; (void)out_size; (void)ws_size;
  const float* x  = (const float*)d_in[0];
  const float* Wq = (const float*)d_in[1];
  const float* Wk = (const float*)d_in[2];
  const float* Wv = (const float*)d_in[3];
  const float* Wp = (const float*)d_in[4];
  float* out = (float*)d_out;

  char* ws = (char*)d_ws;
  const size_t MB = 1ull << 20;
  const long PS1 = 1024l * 1024;   // plane stride, 1024x1024 (shorts)
  const long PS2 = 2048l * 1024;   // plane stride, 2048x1024 (shorts)
  unsigned short* slotp = (unsigned short*)(ws + 0 * MB);   // 12 MB: 3 planes [2048x1024]
  unsigned short* Wqt   = (unsigned short*)(ws + 12 * MB);  // 6 MB: 3 planes [c][d]
  unsigned short* Wkt   = (unsigned short*)(ws + 18 * MB);  // 6 MB: 3 planes [e][d]
  unsigned short* Wvt   = (unsigned short*)(ws + 24 * MB);  // 4 MB: 2 planes [e][d]
  unsigned short* Wpp   = (unsigned short*)(ws + 28 * MB);  // 4 MB: 2 planes [o][d]
  unsigned short* MtT   = (unsigned short*)(ws + 32 * MB);  // 6 MB: 3 planes [c][e] = (Wk^T Wq)^T
  unsigned short* kqp   = (unsigned short*)(ws + 38 * MB);  // 12 MB: 3 planes [2048x1024]
  unsigned short* W2p   = (unsigned short*)(ws + 50 * MB);  // 4 MB: 2 planes [o][e] = Wp@Wv
  float*          u     = (float*)(ws + 54 * MB);           // 8 MB fp32 [2048x1024]
  float*          topw  = (float*)(ws + 62 * MB);           // 0.5 MB
  int*            topi  = (int*)(ws + 62 * MB + 512 * 1024);// 0.5 MB -> 63 MB total (<=113 validated)

  // 1. pool + split3 slots (x read once here)
  poolsplit_k<<<2048, 256, 0, stream>>>(x, slotp);
  // 2. transpose+split weights
  split_t_k<<<dim3(16, 16), 256, 0, stream>>>(Wq, Wqt, PS1, 3);
  split_t_k<<<dim3(16, 16), 256, 0, stream>>>(Wk, Wkt, PS1, 3);
  split_t_k<<<dim3(16, 16), 256, 0, stream>>>(Wv, Wvt, PS1, 2);
  split_k<<<1024, 256, 0, stream>>>(Wp, Wpp, PS1, 2);
  // 3+5. MtT[c][e] (6-prod split3) ++ W2[o][e] (3-prod split2), z-fused, 512 blocks
  gemm35_k<<<dim3(16, 16, 2), 256, 0, stream>>>(Wqt, Wkt, Wpp, Wvt, MtT, W2p, PS1);
  // 4+6. kq[s][c] (6-prod split3) ++ u[s][o] (3-prod fp32), 128^2 m97 tiles, 256 blocks
  gemm46_k<<<dim3(8, 16, 2), 256, 0, stream>>>(slotp, PS2, MtT, W2p, PS1, kqp, u);
  // 7. fused scores (6-product, dbuf 2-phase) + top-8 + softmax
  scores_topk_k<<<256, 512, 0, stream>>>(x, kqp, topw, topi);
  // 8. gather + 0.5 scale
  gatherout_k<<<16384, 256, 0, stream>>>(u, topw, topi, out);
}

// Round 7
// 359.996 us; speedup vs baseline: 1.1628x; 1.0052x over previous
//
#include <hip/hip_runtime.h>
#include <cstdint>
#include <cstddef>

#define Tt 2048
#define Cc 1024
#define Ss 256

using short8 = __attribute__((ext_vector_type(8))) short;
using f32x4  = __attribute__((ext_vector_type(4))) float;
typedef const __attribute__((address_space(1))) void* as1_cvp;
typedef __attribute__((address_space(3))) void* as3_vp;

__device__ __forceinline__ unsigned short f2bf(float f) {
  unsigned int u = __float_as_uint(f);
  u += 0x7fffu + ((u >> 16) & 1u);
  return (unsigned short)(u >> 16);
}
__device__ __forceinline__ float bf2f(unsigned short h) {
  return __uint_as_float(((unsigned)h) << 16);
}
// 3-way split: v = h + m + l to ~2^-24 relative
__device__ __forceinline__ void split3(float v, unsigned short& h, unsigned short& m, unsigned short& l) {
  h = f2bf(v);
  float r = v - bf2f(h);
  m = f2bf(r);
  l = f2bf(r - bf2f(m));
}

// LDS short-offset for N-row x 32-short tile, chunk-XOR swizzled (2-way bank
// aliasing on ds_read_b128 = free, m136)
__device__ __forceinline__ int sw32(int row, int q) {
  return row * 32 + ((q ^ ((row >> 1) & 3)) << 3);
}

// slots planes = split3(mean over 8 consecutive t rows)
__global__ __launch_bounds__(256) void poolsplit_k(const float* __restrict__ x, unsigned short* __restrict__ sp) {
  const long PS2 = 2048l * 1024;
  const int sli = blockIdx.x;           // b*256+s
  const int c = threadIdx.x << 2;
  const float* src = x + (size_t)sli * 8 * Cc + c;
  float a[4] = {0.f, 0.f, 0.f, 0.f};
#pragma unroll
  for (int j = 0; j < 8; j++) {
    float4 v = *(const float4*)(src + (size_t)j * Cc);
    a[0] += v.x; a[1] += v.y; a[2] += v.z; a[3] += v.w;
  }
  unsigned short h[4], m[4], l[4];
#pragma unroll
  for (int e = 0; e < 4; e++) split3(a[e] * 0.125f, h[e], m[e], l[e]);
  size_t o = (size_t)sli * Cc + c;
  *(uint2*)&sp[o]           = uint2{(unsigned)h[0] | ((unsigned)h[1] << 16), (unsigned)h[2] | ((unsigned)h[3] << 16)};
  *(uint2*)&sp[o + PS2]     = uint2{(unsigned)m[0] | ((unsigned)m[1] << 16), (unsigned)m[2] | ((unsigned)m[3] << 16)};
  *(uint2*)&sp[o + 2 * PS2] = uint2{(unsigned)l[0] | ((unsigned)l[1] << 16), (unsigned)l[2] | ((unsigned)l[3] << 16)};
}

// Transpose + split, z-fused over {Wq->Wqt(3), Wk->Wkt(3), Wv->Wvt(2)}.
__global__ __launch_bounds__(256) void split_t3_k(const float* __restrict__ Wq, const float* __restrict__ Wk,
                                                  const float* __restrict__ Wv,
                                                  unsigned short* __restrict__ Wqt, unsigned short* __restrict__ Wkt,
                                                  unsigned short* __restrict__ Wvt, long pstride) {
  __shared__ unsigned short th[64][68], tm[64][68], tl[64][68];
  const int z = blockIdx.z;
  const float* src = (z == 0) ? Wq : (z == 1) ? Wk : Wv;
  unsigned short* dst = (z == 0) ? Wqt : (z == 1) ? Wkt : Wvt;
  const int npl = (z == 2) ? 2 : 3;
  const int r0 = blockIdx.y << 6, c0 = blockIdx.x << 6;
  const int tid = threadIdx.x;
#pragma unroll
  for (int p = 0; p < 4; p++) {
    int r = (p << 4) + (tid >> 4);
    int c = (tid & 15) << 2;
    float4 v = *(const float4*)&src[(size_t)(r0 + r) * Cc + c0 + c];
    unsigned short h, m, l;
    split3(v.x, h, m, l); th[c + 0][r] = h; tm[c + 0][r] = m; tl[c + 0][r] = l;
    split3(v.y, h, m, l); th[c + 1][r] = h; tm[c + 1][r] = m; tl[c + 1][r] = l;
    split3(v.z, h, m, l); th[c + 2][r] = h; tm[c + 2][r] = m; tl[c + 2][r] = l;
    split3(v.w, h, m, l); th[c + 3][r] = h; tm[c + 3][r] = m; tl[c + 3][r] = l;
  }
  __syncthreads();
#pragma unroll
  for (int p = 0; p < 4; p++) {
    int r = (p << 4) + (tid >> 4);      // dst row = src col
    int c = (tid & 15) << 2;
    size_t o = (size_t)(c0 + r) * Cc + r0 + c;
    *(uint2*)&dst[o] = uint2{(unsigned)th[r][c] | ((unsigned)th[r][c+1] << 16),
                             (unsigned)th[r][c+2] | ((unsigned)th[r][c+3] << 16)};
    *(uint2*)&dst[o + pstride] = uint2{(unsigned)tm[r][c] | ((unsigned)tm[r][c+1] << 16),
                                       (unsigned)tm[r][c+2] | ((unsigned)tm[r][c+3] << 16)};
    if (npl == 3)
      *(uint2*)&dst[o + 2 * pstride] = uint2{(unsigned)tl[r][c] | ((unsigned)tl[r][c+1] << 16),
                                             (unsigned)tl[r][c+2] | ((unsigned)tl[r][c+3] << 16)};
  }
}

// Plain split, npl planes
__global__ __launch_bounds__(256) void split_k(const float* __restrict__ src, unsigned short* __restrict__ dst,
                                               long pstride, int npl) {
  int id = blockIdx.x * 256 + threadIdx.x;
  int c = id << 2;
  float4 v = *(const float4*)&src[c];
  unsigned short h[4], m[4], l[4];
  split3(v.x, h[0], m[0], l[0]); split3(v.y, h[1], m[1], l[1]);
  split3(v.z, h[2], m[2], l[2]); split3(v.w, h[3], m[3], l[3]);
  *(uint2*)&dst[c] = uint2{(unsigned)h[0] | ((unsigned)h[1] << 16), (unsigned)h[2] | ((unsigned)h[3] << 16)};
  *(uint2*)&dst[c + pstride] = uint2{(unsigned)m[0] | ((unsigned)m[1] << 16), (unsigned)m[2] | ((unsigned)m[3] << 16)};
  if (npl == 3)
    *(uint2*)&dst[c + 2 * pstride] = uint2{(unsigned)l[0] | ((unsigned)l[1] << 16), (unsigned)l[2] | ((unsigned)l[3] << 16)};
}

// Combine two fp32 partial-product arrays and split3 into 3 bf16 planes.
__global__ __launch_bounds__(256) void kqsplit_k(const float* __restrict__ a, const float* __restrict__ bsrc,
                                                 unsigned short* __restrict__ dst) {
  const long PS2 = 2048l * 1024;
  int id = blockIdx.x * 256 + threadIdx.x;
  int c = id << 2;
  float4 va = *(const float4*)&a[c];
  float4 vb = *(const float4*)&bsrc[c];
  float s0 = va.x + vb.x, s1 = va.y + vb.y, s2 = va.z + vb.z, s3 = va.w + vb.w;
  unsigned short h[4], m[4], l[4];
  split3(s0, h[0], m[0], l[0]); split3(s1, h[1], m[1], l[1]);
  split3(s2, h[2], m[2], l[2]); split3(s3, h[3], m[3], l[3]);
  *(uint2*)&dst[c]           = uint2{(unsigned)h[0] | ((unsigned)h[1] << 16), (unsigned)h[2] | ((unsigned)h[3] << 16)};
  *(uint2*)&dst[c + PS2]     = uint2{(unsigned)m[0] | ((unsigned)m[1] << 16), (unsigned)m[2] | ((unsigned)m[3] << 16)};
  *(uint2*)&dst[c + 2 * PS2] = uint2{(unsigned)l[0] | ((unsigned)l[1] << 16), (unsigned)l[2] | ((unsigned)l[3] << 16)};
}

// Multi-plane split GEMM body, 64x64 tile, BK=32, 4 waves of 32x32.
// Round-5 VERIFIED body, unchanged.
template<int NT, int SPLIT_OUT>
__device__ __forceinline__ void gemm3_body(unsigned short* LDS,
                                           const unsigned short* __restrict__ Ap, long apl,
                                           const unsigned short* __restrict__ Bp, long bpl,
                                           float* __restrict__ C,
                                           unsigned short* __restrict__ Cs, long cpl,
                                           float scale) {
  constexpr int NPL = (NT == 6) ? 3 : 2;
  constexpr int BUFS = 2 * NPL * 2048;              // shorts per buffer
  const int tid = threadIdx.x, lane = tid & 63, wid = tid >> 6;
  const int m0 = blockIdx.y << 6, n0 = blockIdx.x << 6;

  const unsigned short* sp[2 * NPL];
  int dof[2 * NPL];                                  // byte offset within a buffer
#pragma unroll
  for (int i = 0; i < 2 * NPL; i++) {
    int s = wid * 2 * NPL + i;           // [0, 8*NPL)
    int tile = s >> 2;                   // [0, 2*NPL)
    int ci = ((s & 3) << 6) | lane;      // chunk in tile [0,256)
    int row = ci >> 2;
    int q = (ci & 3) ^ ((row >> 1) & 3); // source chunk for swizzled slot
    int isB = tile >= NPL;
    int pl = isB ? tile - NPL : tile;
    const unsigned short* base = isB ? (Bp + (size_t)pl * bpl) : (Ap + (size_t)pl * apl);
    int r0 = isB ? n0 : m0;
    sp[i] = base + (size_t)(r0 + row) * Cc + (q << 3);
    dof[i] = (tile * 2048 + ((s & 3) << 9)) * 2;
  }

  const int wm = (wid >> 1) << 5, wn = (wid & 1) << 5;
  const int lm = lane & 15, lq = lane >> 4;
  constexpr int PA[6] = {0, 0, 1, 0, 2, 1};
  constexpr int PB[6] = {0, 1, 0, 2, 0, 1};
  const f32x4 zero = {0.f, 0.f, 0.f, 0.f};
  f32x4 acc[2][2] = {{zero, zero}, {zero, zero}};

  // prologue: stage K-tile 0 into buf 0
#pragma unroll
  for (int i = 0; i < 2 * NPL; i++) {
    __builtin_amdgcn_global_load_lds((as1_cvp)sp[i], (as3_vp)((char*)LDS + dof[i]), 16, 0, 0);
    sp[i] += 32;
  }
  __syncthreads();

  int cur = 0;
  for (int k0 = 0; k0 < Cc; k0 += 32) {
    if (k0 + 32 < Cc) {                  // issue next tile's loads (prefetch)
      const int nb = (cur ^ 1) * (BUFS * 2);
#pragma unroll
      for (int i = 0; i < 2 * NPL; i++) {
        __builtin_amdgcn_global_load_lds((as1_cvp)sp[i], (as3_vp)((char*)LDS + nb + dof[i]), 16, 0, 0);
        sp[i] += 32;
      }
    }
    const int cb = cur * BUFS;           // shorts
    short8 af[2][NPL], bf[2][NPL];
#pragma unroll
    for (int i = 0; i < 2; i++)
#pragma unroll
      for (int p = 0; p < NPL; p++) {
        af[i][p] = *(const short8*)&LDS[cb + p * 2048 + sw32(wm + (i << 4) + lm, lq)];
        bf[i][p] = *(const short8*)&LDS[cb + (NPL + p) * 2048 + sw32(wn + (i << 4) + lm, lq)];
      }
#pragma unroll
    for (int i = 0; i < 2; i++)
#pragma unroll
      for (int j = 0; j < 2; j++)
#pragma unroll
        for (int t = 0; t < NT; t++)
          acc[i][j] = __builtin_amdgcn_mfma_f32_16x16x32_bf16(af[i][PA[t]], bf[j][PB[t]], acc[i][j], 0, 0, 0);
    __syncthreads();                     // drains vmcnt(0): next buf staged
    cur ^= 1;
  }
  // C/D: col = lane&15, row = (lane>>4)*4 + reg  [m89-verified]
#pragma unroll
  for (int i = 0; i < 2; i++)
#pragma unroll
    for (int j = 0; j < 2; j++)
#pragma unroll
      for (int r = 0; r < 4; r++) {
        int gr = m0 + wm + (i << 4) + (lq << 2) + r;
        int gc = n0 + wn + (j << 4) + lm;
        size_t o = (size_t)gr * Cc + gc;
        float v = acc[i][j][r] * scale;
        if (SPLIT_OUT) {
          unsigned short h = f2bf(v);
          float rr = v - bf2f(h);
          unsigned short mm2 = f2bf(rr);
          Cs[o] = h;
          Cs[o + cpl] = mm2;
          if (NPL == 3) Cs[o + 2 * (size_t)cpl] = f2bf(rr - bf2f(mm2));
        } else {
          C[o] = v;
        }
      }
}

// m97-structure body: 128x128 tile, BK=32, 4 waves each 64x64 (acc[4][4]).
// Round-5 VERIFIED body; ONLY delta: ALT selects the product table
// (ALT=0: hh,hm,mh prefix; ALT=1: hm,mh,mm — for the (h,m) partial of the
// 6-product partition hh+hl+lh (ALT=0 on planes (h,l) via doubled strides)
// plus hm+mh+mm (ALT=1 on planes (h,m))).
template<int NT, int SPLIT_OUT, int ALT>
__device__ __forceinline__ void gemm128_body(unsigned short* LDS,
                                             const unsigned short* __restrict__ Ap, long apl,
                                             const unsigned short* __restrict__ Bp, long bpl,
                                             float* __restrict__ C,
                                             unsigned short* __restrict__ Cs, long cpl,
                                             float scale) {
  constexpr int NPL = (NT == 6) ? 3 : 2;
  constexpr int BUFS = 2 * NPL * 4096;              // shorts per buffer (tile = 128x32)
  const int tid = threadIdx.x, lane = tid & 63, wid = tid >> 6;
  const int m0 = blockIdx.y << 7, n0 = blockIdx.x << 7;

  // staging: 2*NPL tiles x 8 chunks of 1KB; 4*NPL chunks per wave
  const unsigned short* sp[4 * NPL];
  int dof[4 * NPL];
#pragma unroll
  for (int i = 0; i < 4 * NPL; i++) {
    int s = wid * 4 * NPL + i;           // [0, 16*NPL)
    int tile = s >> 3;                   // [0, 2*NPL)
    int ci = ((s & 7) << 6) | lane;      // [0,512) position in tile
    int row = ci >> 2;                   // [0,128)
    int q = (ci & 3) ^ ((row >> 1) & 3);
    int isB = tile >= NPL;
    int pl = isB ? tile - NPL : tile;
    const unsigned short* base = isB ? (Bp + (size_t)pl * bpl) : (Ap + (size_t)pl * apl);
    int r0 = isB ? n0 : m0;
    sp[i] = base + (size_t)(r0 + row) * Cc + (q << 3);
    dof[i] = (tile * 4096 + ((s & 7) << 9)) * 2;
  }

  const int wr = (wid >> 1) << 6, wc = (wid & 1) << 6;
  const int lm = lane & 15, lq = lane >> 4;
  constexpr int PAt[2][6] = {{0, 0, 1, 0, 2, 1}, {0, 1, 1, 0, 0, 0}};
  constexpr int PBt[2][6] = {{0, 1, 0, 2, 0, 1}, {1, 0, 1, 0, 0, 0}};
  const f32x4 zero = {0.f, 0.f, 0.f, 0.f};
  f32x4 acc[4][4];
#pragma unroll
  for (int i = 0; i < 4; i++)
#pragma unroll
    for (int j = 0; j < 4; j++) acc[i][j] = zero;

  // prologue: stage K-tile 0 into buf 0
#pragma unroll
  for (int i = 0; i < 4 * NPL; i++) {
    __builtin_amdgcn_global_load_lds((as1_cvp)sp[i], (as3_vp)((char*)LDS + dof[i]), 16, 0, 0);
    sp[i] += 32;
  }
  __syncthreads();

  int cur = 0;
  for (int k0 = 0; k0 < Cc; k0 += 32) {
    if (k0 + 32 < Cc) {                  // prefetch next tile
      const int nb = (cur ^ 1) * (BUFS * 2);
#pragma unroll
      for (int i = 0; i < 4 * NPL; i++) {
        __builtin_amdgcn_global_load_lds((as1_cvp)sp[i], (as3_vp)((char*)LDS + nb + dof[i]), 16, 0, 0);
        sp[i] += 32;
      }
    }
    const int cb = cur * BUFS;           // shorts
    short8 af[4][NPL];
#pragma unroll
    for (int i = 0; i < 4; i++)
#pragma unroll
      for (int p = 0; p < NPL; p++)
        af[i][p] = *(const short8*)&LDS[cb + p * 4096 + sw32(wr + (i << 4) + lm, lq)];
#pragma unroll
    for (int j = 0; j < 4; j++) {
      short8 bf[NPL];
#pragma unroll
      for (int p = 0; p < NPL; p++)
        bf[p] = *(const short8*)&LDS[cb + (NPL + p) * 4096 + sw32(wc + (j << 4) + lm, lq)];
#pragma unroll
      for (int i = 0; i < 4; i++)
#pragma unroll
        for (int t = 0; t < NT; t++)
          acc[i][j] = __builtin_amdgcn_mfma_f32_16x16x32_bf16(af[i][PAt[ALT][t]], bf[PBt[ALT][t]], acc[i][j], 0, 0, 0);
    }
    __syncthreads();
    cur ^= 1;
  }
  // epilogue
#pragma unroll
  for (int i = 0; i < 4; i++)
#pragma unroll
    for (int j = 0; j < 4; j++)
#pragma unroll
      for (int r = 0; r < 4; r++) {
        int gr = m0 + wr + (i << 4) + (lq << 2) + r;
        int gc = n0 + wc + (j << 4) + lm;
        size_t o = (size_t)gr * Cc + gc;
        float v = acc[i][j][r] * scale;
        if (SPLIT_OUT) {
          unsigned short h = f2bf(v);
          float rr = v - bf2f(h);
          unsigned short mm2 = f2bf(rr);
          Cs[o] = h;
          Cs[o + cpl] = mm2;
          if (NPL == 3) Cs[o + 2 * (size_t)cpl] = f2bf(rr - bf2f(mm2));
        } else {
          C[o] = v;
        }
      }
}

// steps 3+5 fused (round-5 verified): z=0 MtT (6-prod split3), z=1 W2
// (3-prod split2). 64^2 tiles, 512 blocks -> 2 blocks/CU.
__global__ __launch_bounds__(256) void gemm35_k(const unsigned short* __restrict__ Wqt,
                                                const unsigned short* __restrict__ Wkt,
                                                const unsigned short* __restrict__ Wpp,
                                                const unsigned short* __restrict__ Wvt,
                                                unsigned short* __restrict__ MtT,
                                                unsigned short* __restrict__ W2p, long ps1) {
  __shared__ unsigned short LDS[24576];             // 48 KB = dbuf for NT=6
  if (blockIdx.z == 0)
    gemm3_body<6, 1>(LDS, Wqt, ps1, Wkt, ps1, nullptr, MtT, ps1, 1.0f);
  else
    gemm3_body<3, 1>(LDS, Wpp, ps1, Wvt, ps1, nullptr, W2p, ps1, 1.0f);
}

// steps 4+6, 6-product kq partitioned into two NPL=2 slices + u:
//   z=0: kqfA = hh+hl+lh  (planes (h,l) via DOUBLED plane strides, std table)
//   z=1: kqfB = hm+mh+mm  (planes (h,m), ALT table)
//   z=2: u    = hh+hm+mh  (round-5 z=1 verbatim)
// All NPL=2 -> LDS 64 KB -> 2 blocks/CU (was 96 KB, 1 block/CU).
__global__ __launch_bounds__(256) void gemm46_k(const unsigned short* __restrict__ slotp, long ps2,
                                                const unsigned short* __restrict__ MtT,
                                                const unsigned short* __restrict__ W2p, long ps1,
                                                float* __restrict__ kqfA, float* __restrict__ kqfB,
                                                float* __restrict__ u) {
  __shared__ unsigned short LDS[32768];              // 64 KB = dbuf for NPL=2
  if (blockIdx.z == 0)
    gemm128_body<3, 0, 0>(LDS, slotp, 2 * ps2, MtT, 2 * ps1, kqfA, nullptr, 0, 1.0f);
  else if (blockIdx.z == 1)
    gemm128_body<3, 0, 1>(LDS, slotp, ps2, MtT, ps1, kqfB, nullptr, 0, 1.0f);
  else
    gemm128_body<3, 0, 0>(LDS, slotp, ps2, W2p, ps1, u, nullptr, 0, 1.0f);
}

// Fused scores + top-8 + softmax (round-2/5 verified, ~132 us).
__global__ __launch_bounds__(512) void scores_topk_k(const float* __restrict__ x,
                                                     const unsigned short* __restrict__ kqp,
                                                     float* __restrict__ topw, int* __restrict__ topi) {
  __shared__ __align__(16) char smem[125952];
  unsigned short* lds16 = (unsigned short*)smem;
  float* sc = (float*)smem;                         // tail: 64x260 fp32

  const int tid = threadIdx.x, lane = tid & 63, wid = tid >> 6;
  const int bid = blockIdx.x;
  const int b = bid & 7, tt = bid >> 3;

  // kq staging: 48 slots (3 planes x 16 sub-tiles), 6 per wave
  const char* ksrc[6];
  int kdst[6];                                      // byte offset within a kq buffer
#pragma unroll
  for (int i = 0; i < 6; i++) {
    int s = wid * 6 + i;                 // [0,48)
    int p = s >> 4, sub = s & 15;
    int ci = (sub << 6) | lane;          // [0,1024)
    int row = ci >> 2;
    int q = (ci & 3) ^ ((row >> 1) & 3);
    ksrc[i] = (const char*)(kqp + (size_t)p * (2048l * 1024) + ((size_t)b * Ss + row) * Cc + (q << 3));
    kdst[i] = p * 16384 + sub * 1024;
  }
  const int spr = tid >> 3, spk = (tid & 7) << 2;   // x-tile: row, col(4 floats)
  const float* xsrc = x + ((size_t)b * Tt + (size_t)tt * 64 + spr) * Cc + spk;

  const int wm = (wid & 1) << 5;         // row group
  const int wn = (wid >> 1) << 6;        // col group (x4)
  const int lm = lane & 15, lq = lane >> 4;
  const int XP = 49152;                  // x-plane base (shorts); buf stride 6912, plane stride 2304

  constexpr int PA[6] = {0, 0, 1, 0, 2, 1};
  constexpr int PB[6] = {0, 1, 0, 2, 0, 1};
  const f32x4 zero = {0.f, 0.f, 0.f, 0.f};
  f32x4 acc[2][4];
#pragma unroll
  for (int i = 0; i < 2; i++)
#pragma unroll
    for (int j = 0; j < 4; j++) acc[i][j] = zero;

  // ---- prologue: stage K-tile 0 (x -> regs -> split -> planes buf0; kq -> buf0)
  {
    float4 xv = *(const float4*)xsrc; xsrc += 32;
#pragma unroll
    for (int i = 0; i < 6; i++) {
      __builtin_amdgcn_global_load_lds((as1_cvp)ksrc[i], (as3_vp)(smem + kdst[i]), 16, 0, 0);
      ksrc[i] += 64;
    }
    unsigned short h[4], m[4], l[4];
    split3(xv.x, h[0], m[0], l[0]); split3(xv.y, h[1], m[1], l[1]);
    split3(xv.z, h[2], m[2], l[2]); split3(xv.w, h[3], m[3], l[3]);
    int o = XP + spr * 36 + spk;
    *(uint2*)&lds16[o]        = uint2{(unsigned)h[0] | ((unsigned)h[1] << 16), (unsigned)h[2] | ((unsigned)h[3] << 16)};
    *(uint2*)&lds16[o + 2304] = uint2{(unsigned)m[0] | ((unsigned)m[1] << 16), (unsigned)m[2] | ((unsigned)m[3] << 16)};
    *(uint2*)&lds16[o + 4608] = uint2{(unsigned)l[0] | ((unsigned)l[1] << 16), (unsigned)l[2] | ((unsigned)l[3] << 16)};
  }
  __syncthreads();

  int cur = 0;
  for (int ks = 0; ks < 32; ks++) {
    const int nb = cur ^ 1;
    float4 xv2;
    if (ks < 31) {                       // issue next tile's loads (prefetch)
      xv2 = *(const float4*)xsrc; xsrc += 32;
#pragma unroll
      for (int i = 0; i < 6; i++) {
        __builtin_amdgcn_global_load_lds((as1_cvp)ksrc[i], (as3_vp)(smem + nb * 49152 + kdst[i]), 16, 0, 0);
        ksrc[i] += 64;
      }
    }
    // ---- compute current tile
    const int xb = XP + cur * 6912;      // shorts
    const int kb = cur * 24576;          // shorts
    short8 afr[2][3], bfr[4][3];
#pragma unroll
    for (int i = 0; i < 2; i++)
#pragma unroll
      for (int p = 0; p < 3; p++)
        afr[i][p] = *(const short8*)&lds16[xb + p * 2304 + (wm + (i << 4) + lm) * 36 + (lq << 3)];
#pragma unroll
    for (int j = 0; j < 4; j++) {
      int br = wn + (j << 4) + lm;
      int bo = (br << 5) + ((lq ^ ((br >> 1) & 3)) << 3);
#pragma unroll
      for (int p = 0; p < 3; p++)
        bfr[j][p] = *(const short8*)&lds16[kb + p * 8192 + bo];
    }
#pragma unroll
    for (int i = 0; i < 2; i++)
#pragma unroll
      for (int j = 0; j < 4; j++)
#pragma unroll
        for (int t = 0; t < 6; t++)
          acc[i][j] = __builtin_amdgcn_mfma_f32_16x16x32_bf16(afr[i][PA[t]], bfr[j][PB[t]], acc[i][j], 0, 0, 0);
    // ---- split next x tile into planes buf nb (write-late; regs only)
    if (ks < 31) {
      unsigned short h[4], m[4], l[4];
      split3(xv2.x, h[0], m[0], l[0]); split3(xv2.y, h[1], m[1], l[1]);
      split3(xv2.z, h[2], m[2], l[2]); split3(xv2.w, h[3], m[3], l[3]);
      int o = XP + nb * 6912 + spr * 36 + spk;
      *(uint2*)&lds16[o]        = uint2{(unsigned)h[0] | ((unsigned)h[1] << 16), (unsigned)h[2] | ((unsigned)h[3] << 16)};
      *(uint2*)&lds16[o + 2304] = uint2{(unsigned)m[0] | ((unsigned)m[1] << 16), (unsigned)m[2] | ((unsigned)m[3] << 16)};
      *(uint2*)&lds16[o + 4608] = uint2{(unsigned)l[0] | ((unsigned)l[1] << 16), (unsigned)l[2] | ((unsigned)l[3] << 16)};
    }
    __syncthreads();                     // drains vmcnt(0): kq buf nb staged; plane writes visible
    cur ^= 1;
  }

  // scores -> LDS (scaled 1/32), then per-wave top-8 + softmax
#pragma unroll
  for (int i = 0; i < 2; i++)
#pragma unroll
    for (int j = 0; j < 4; j++)
#pragma unroll
      for (int r = 0; r < 4; r++)
        sc[(wm + (i << 4) + (lq << 2) + r) * 260 + wn + (j << 4) + lm] = acc[i][j][r] * 0.03125f;
  __syncthreads();

  for (int r2 = 0; r2 < 8; r2++) {
    int row = (wid << 3) + r2;
    float4 v = *(const float4*)(sc + row * 260 + (lane << 2));
    float cand[4] = {v.x, v.y, v.z, v.w};
    float topv[8]; int tops[8];
#pragma unroll
    for (int k = 0; k < 8; k++) {
      float bv = -1e30f; int bs = 1 << 20;
#pragma unroll
      for (int e = 0; e < 4; e++) {
        int s = (lane << 2) + e;
        if (cand[e] > bv || (cand[e] == bv && s < bs)) { bv = cand[e]; bs = s; }
      }
#pragma unroll
      for (int m = 32; m >= 1; m >>= 1) {
        float ov = __shfl_xor(bv, m, 64);
        int   os = __shfl_xor(bs, m, 64);
        if (ov > bv || (ov == bv && os < bs)) { bv = ov; bs = os; }
      }
      topv[k] = bv; tops[k] = bs;
      if ((bs >> 2) == lane) cand[bs & 3] = -1e30f;
    }
    float mx = topv[0];
    float sum = 0.f;
#pragma unroll
    for (int k = 0; k < 8; k++) sum += expf(topv[k] - mx);
    if (lane < 8) {
      float myv = topv[0]; int myi = tops[0];
#pragma unroll
      for (int k = 1; k < 8; k++) if (lane == k) { myv = topv[k]; myi = tops[k]; }
      size_t trow = (size_t)b * Tt + (size_t)tt * 64 + row;
      topw[trow * 8 + lane] = expf(myv - mx) / sum;
      topi[trow * 8 + lane] = myi;
    }
  }
}

// out[row,:] = 0.5 * sum_k w_k * u[b*256+idx_k, :]   (fp32)
// Batch->XCD swizzle (perf-only, bijective): each batch's blocks land on one
// XCD so its 1 MB u slice stays L2-local.
__global__ __launch_bounds__(256) void gatherout_k(const float* __restrict__ u, const float* __restrict__ topw,
                                                   const int* __restrict__ topi, float* __restrict__ out) {
  __shared__ float w[8];
  __shared__ int  id8[8];
  const int bid = blockIdx.x;
  const int row = ((bid & 7) << 11) | (bid >> 3);   // bijective: 8 x 2048
  const int b = bid & 7;
  if (threadIdx.x < 8) {
    w[threadIdx.x]   = topw[(size_t)row * 8 + threadIdx.x];
    id8[threadIdx.x] = topi[(size_t)row * 8 + threadIdx.x];
  }
  __syncthreads();
  int c = threadIdx.x << 2;
  float ax = 0.f, ay = 0.f, az = 0.f, aw = 0.f;
#pragma unroll
  for (int j = 0; j < 8; j++) {
    const float4 vv = *(const float4*)&u[((size_t)(b << 8) + id8[j]) * Cc + c];
    float wj = w[j];
    ax = fmaf(wj, vv.x, ax); ay = fmaf(wj, vv.y, ay);
    az = fmaf(wj, vv.z, az); aw = fmaf(wj, vv.w, aw);
  }
  *(float4*)&out[(size_t)row * Cc + c] = make_float4(ax * 0.5f, ay * 0.5f, az * 0.5f, aw * 0.5f);
}

extern "C" void kernel_launch(void* const* d_in, const int* in_sizes, int n_in,
                              void* d_out, int out_size, void* d_ws, size_t ws_size,
                              hipStream_t stream) {
  (void)in_sizes; (void)n_in; (void)out_size; (void)ws_size;
  const float* x  = (const float*)d_in[0];
  const float* Wq = (const float*)d_in[1];
  const float* Wk = (const float*)d_in[2];
  const float* Wv = (const float*)d_in[3];
  const float* Wp = (const float*)d_in[4];
  float* out = (float*)d_out;

  char* ws = (char*)d_ws;
  const size_t MB = 1ull << 20;
  const long PS1 = 1024l * 1024;   // plane stride, 1024x1024 (shorts)
  const long PS2 = 2048l * 1024;   // plane stride, 2048x1024 (shorts)
  unsigned short* slotp = (unsigned short*)(ws + 0 * MB);   // 12 MB: 3 planes [2048x1024]
  unsigned short* Wqt   = (unsigned short*)(ws + 12 * MB);  // 6 MB: 3 planes [c][d]
  unsigned short* Wkt   = (unsigned short*)(ws + 18 * MB);  // 6 MB: 3 planes [e][d]
  unsigned short* Wvt   = (unsigned short*)(ws + 24 * MB);  // 4 MB: 2 planes [e][d]
  unsigned short* Wpp   = (unsigned short*)(ws + 28 * MB);  // 4 MB: 2 planes [o][d]
  unsigned short* MtT   = (unsigned short*)(ws + 32 * MB);  // 6 MB: 3 planes [c][e] = (Wk^T Wq)^T
  unsigned short* kqp   = (unsigned short*)(ws + 38 * MB);  // 12 MB: 3 planes [2048x1024]
  unsigned short* W2p   = (unsigned short*)(ws + 50 * MB);  // 4 MB: 2 planes [o][e] = Wp@Wv
  float*          u     = (float*)(ws + 54 * MB);           // 8 MB fp32 [2048x1024]
  float*          topw  = (float*)(ws + 62 * MB);           // 0.5 MB
  int*            topi  = (int*)(ws + 62 * MB + 512 * 1024);// 0.5 MB
  float*          kqfA  = (float*)(ws + 63 * MB);           // 8 MB fp32 partial (hh+hl+lh)
  float*          kqfB  = (float*)(ws + 71 * MB);           // 8 MB fp32 partial (hm+mh+mm) -> 79 MB total (<=113)

  // 1. pool + split3 slots (x read once here)
  poolsplit_k<<<2048, 256, 0, stream>>>(x, slotp);
  // 2. transpose+split weights (z-fused) + Wp plain split
  split_t3_k<<<dim3(16, 16, 3), 256, 0, stream>>>(Wq, Wk, Wv, Wqt, Wkt, Wvt, PS1);
  split_k<<<1024, 256, 0, stream>>>(Wp, Wpp, PS1, 2);
  // 3+5. MtT (6-prod split3) ++ W2 (3-prod split2), 64^2 tiles, 512 blocks (round-5 verified)
  gemm35_k<<<dim3(16, 16, 2), 256, 0, stream>>>(Wqt, Wkt, Wpp, Wvt, MtT, W2p, PS1);
  // 4+6. kq partials (2 x NPL=2 slices) ++ u, 128^2 tiles, 384 blocks, 2 blocks/CU
  gemm46_k<<<dim3(8, 16, 3), 256, 0, stream>>>(slotp, PS2, MtT, W2p, PS1, kqfA, kqfB, u);
  // 4b. kq = split3(kqfA + kqfB)
  kqsplit_k<<<2048, 256, 0, stream>>>(kqfA, kqfB, kqp);
  // 7. fused scores (6-product, dbuf 2-phase) + top-8 + softmax
  scores_topk_k<<<256, 512, 0, stream>>>(x, kqp, topw, topi);
  // 8. gather + 0.5 scale (batch->XCD swizzled)
  gatherout_k<<<16384, 256, 0, stream>>>(u, topw, topi, out);
}